// Round 1
// baseline (4072.806 us; speedup 1.0000x reference)
//
#include <hip/hip_runtime.h>
#include <hip/hip_bf16.h>

typedef __bf16 bf16_t;
typedef __bf16 bf16x8 __attribute__((ext_vector_type(8)));
typedef float  f32x4  __attribute__((ext_vector_type(4)));

#define DEV static __device__ __forceinline__

DEV void gload16(const bf16_t* g, bf16_t* l) {
    __builtin_amdgcn_global_load_lds(
        (const __attribute__((address_space(1))) void*)g,
        (__attribute__((address_space(3))) void*)l, 16, 0, 0);
}

enum { EPI_F32 = 0, EPI_BF16 = 1, EPI_RES = 2, EPI_GELU = 3 };

// C = A * Bt^T.  A: [M,Kd] row-major (bf16), Bt: [N,Kd] row-major (bf16).
// 128x128 tile, BK=32, 4 waves (2x2), mfma_f32_16x16x32_bf16.
template<int EPI, bool DUAL>
__global__ __launch_bounds__(256)
void gemm_bt(const bf16_t* __restrict__ A, const bf16_t* __restrict__ Bt,
             const bf16_t* __restrict__ Bt2, void* __restrict__ Cout,
             int M, int N, int Kd, int lda, int ldb, int ldc,
             long sAz, long sBz, long sCz,
             const float* __restrict__ res, const float* __restrict__ gate,
             int gateStride, int rowsPerB)
{
    const int tid = threadIdx.x;
    const int l   = tid & 63;
    const int w   = tid >> 6;
    const int wr  = w >> 1, wc = w & 1;
    const long m0 = (long)blockIdx.y * 128;
    const long n0 = (long)blockIdx.x * 128;
    const int  z  = blockIdx.z;

    A  += (long)z * sAz;
    Bt += (long)z * sBz;

    __shared__ bf16_t As[128 * 32];
    __shared__ bf16_t Bs[128 * 32];
    __shared__ bf16_t Bs2[DUAL ? 128 * 32 : 4];

    const int srow = w * 16 + (l >> 2);     // staging row within tile (round 0)
    const int scol = (l & 3) * 8;           // k-chunk (8 bf16 = 16B)
    const bf16_t* Ag  = A  + (m0 + srow) * (long)lda + scol;
    const bf16_t* Bg  = Bt + (n0 + srow) * (long)ldb + scol;
    const bf16_t* Bg2 = nullptr;
    if constexpr (DUAL) Bg2 = Bt2 + (n0 + srow) * (long)ldb + scol;

    bf16_t* ldsA  = As + w * 512;   // wave-uniform base; HW adds lane*16B
    bf16_t* ldsB  = Bs + w * 512;
    bf16_t* ldsB2 = nullptr;
    if constexpr (DUAL) ldsB2 = Bs2 + w * 512;

    f32x4 acc[16];
    f32x4 acc2[DUAL ? 16 : 1];
    const f32x4 fz = {0.f, 0.f, 0.f, 0.f};
#pragma unroll
    for (int i = 0; i < 16; i++) acc[i] = fz;
    if constexpr (DUAL) {
#pragma unroll
        for (int i = 0; i < 16; i++) acc2[i] = fz;
    }

    for (int k0 = 0; k0 < Kd; k0 += 32) {
        gload16(Ag + k0,                  ldsA);
        gload16(Ag + k0 + 64 * (long)lda, ldsA + 2048);
        gload16(Bg + k0,                  ldsB);
        gload16(Bg + k0 + 64 * (long)ldb, ldsB + 2048);
        if constexpr (DUAL) {
            gload16(Bg2 + k0,                  ldsB2);
            gload16(Bg2 + k0 + 64 * (long)ldb, ldsB2 + 2048);
        }
        __syncthreads();   // drains vmcnt before barrier

        bf16x8 af[4], bfr[4], bfr2[4];
#pragma unroll
        for (int f = 0; f < 4; f++) {
            af[f]  = *(const bf16x8*)(As + (wr * 64 + f * 16 + (l & 15)) * 32 + (l >> 4) * 8);
            bfr[f] = *(const bf16x8*)(Bs + (wc * 64 + f * 16 + (l & 15)) * 32 + (l >> 4) * 8);
            if constexpr (DUAL)
                bfr2[f] = *(const bf16x8*)(Bs2 + (wc * 64 + f * 16 + (l & 15)) * 32 + (l >> 4) * 8);
        }
#pragma unroll
        for (int i = 0; i < 4; i++)
#pragma unroll
            for (int j = 0; j < 4; j++) {
                acc[i * 4 + j] = __builtin_amdgcn_mfma_f32_16x16x32_bf16(af[i], bfr[j], acc[i * 4 + j], 0, 0, 0);
                if constexpr (DUAL)
                    acc2[i * 4 + j] = __builtin_amdgcn_mfma_f32_16x16x32_bf16(af[i], bfr2[j], acc2[i * 4 + j], 0, 0, 0);
            }
        __syncthreads();
    }

    // epilogue: C/D layout col = lane&15, row = (lane>>4)*4 + reg
#pragma unroll
    for (int i = 0; i < 4; i++) {
#pragma unroll
        for (int j = 0; j < 4; j++) {
            f32x4 v = acc[i * 4 + j];
            const long col  = n0 + wc * 64 + j * 16 + (l & 15);
            const long row0 = m0 + wr * 64 + i * 16 + ((l >> 4) * 4);
#pragma unroll
            for (int e = 0; e < 4; e++) {
                const long row = row0 + e;
                const long idx = row * (long)ldc + col + (long)z * sCz;
                const float val = v[e];
                if constexpr (EPI == EPI_F32) {
                    ((float*)Cout)[idx] = val;
                } else if constexpr (EPI == EPI_BF16) {
                    ((bf16_t*)Cout)[idx] = (bf16_t)val;
                } else if constexpr (EPI == EPI_RES) {
                    const int b = (int)(row / rowsPerB);
                    ((float*)Cout)[idx] = res[row * (long)ldc + col] + val * gate[(long)b * gateStride + col];
                } else {  // EPI_GELU: out = gelu(c0) * c1  (tanh approx, JAX default)
                    const float x0  = val;
                    const float x1v = acc2[i * 4 + j][e];
                    const float gl  = 0.5f * x0 * (1.f + tanhf(0.7978845608f * (x0 + 0.044715f * x0 * x0 * x0)));
                    ((bf16_t*)Cout)[idx] = (bf16_t)(gl * x1v);
                }
            }
        }
    }
}

// fp32 [R,C] -> bf16 [C,R] transpose (batched via blockIdx.z)
__global__ __launch_bounds__(256)
void transpose_f2b(const float* __restrict__ in, bf16_t* __restrict__ out,
                   int R, int C, long inStride, long outStride)
{
    __shared__ float tile[32][33];
    in  += (long)blockIdx.z * inStride;
    out += (long)blockIdx.z * outStride;
    const int c0 = blockIdx.x * 32, r0 = blockIdx.y * 32;
    const int tx = threadIdx.x, ty = threadIdx.y;
#pragma unroll
    for (int i = 0; i < 4; i++)
        tile[ty + i * 8][tx] = in[(long)(r0 + ty + i * 8) * C + c0 + tx];
    __syncthreads();
#pragma unroll
    for (int i = 0; i < 4; i++)
        out[(long)(c0 + ty + i * 8) * R + r0 + tx] = (bf16_t)tile[tx][ty + i * 8];
}

// mod = cond @ Wmod + bmod   ([B,D] x [D,3D])
__global__ __launch_bounds__(256)
void modk(const float* __restrict__ cond, const float* __restrict__ W,
          const float* __restrict__ bvec, float* __restrict__ mod, int D, int D3)
{
    const int j = blockIdx.x * 256 + threadIdx.x;
    const int b = blockIdx.y;
    float s = 0.f;
    const float* cb = cond + (long)b * D;
    for (int d = 0; d < D; d++) s += cb[d] * W[(long)d * D3 + j];
    mod[(long)b * D3 + j] = s + bvec[j];
}

// RMSNorm (fp32) + AdaLN scale/shift -> bf16.  One block per row, D=2048.
__global__ __launch_bounds__(256)
void rmsnorm_adaln(const float* __restrict__ xin, const float* __restrict__ mod,
                   bf16_t* __restrict__ out, int D, int T, int D3)
{
    const long row = blockIdx.x;
    const int  b   = (int)(row / T);
    const int  tid = threadIdx.x;
    const float4* x4 = (const float4*)(xin + row * (long)D);
    const float4 v0 = x4[tid], v1 = x4[tid + 256];
    float ss = v0.x * v0.x + v0.y * v0.y + v0.z * v0.z + v0.w * v0.w
             + v1.x * v1.x + v1.y * v1.y + v1.z * v1.z + v1.w * v1.w;
    for (int o = 32; o; o >>= 1) ss += __shfl_down(ss, o, 64);
    __shared__ float red[4];
    if ((tid & 63) == 0) red[tid >> 6] = ss;
    __syncthreads();
    ss = red[0] + red[1] + red[2] + red[3];
    const float rs = rsqrtf(ss / (float)D + 1e-6f);
    const float* sc = mod + (long)b * D3;
    const float* sh = sc + D;
    const float4 s0 = ((const float4*)sc)[tid], s1 = ((const float4*)sc)[tid + 256];
    const float4 h0 = ((const float4*)sh)[tid], h1 = ((const float4*)sh)[tid + 256];
    bf16_t* orow = out + row * (long)D;
    orow[tid * 4 + 0]         = (bf16_t)(v0.x * rs * (1.f + s0.x) + h0.x);
    orow[tid * 4 + 1]         = (bf16_t)(v0.y * rs * (1.f + s0.y) + h0.y);
    orow[tid * 4 + 2]         = (bf16_t)(v0.z * rs * (1.f + s0.z) + h0.z);
    orow[tid * 4 + 3]         = (bf16_t)(v0.w * rs * (1.f + s0.w) + h0.w);
    orow[(tid + 256) * 4 + 0] = (bf16_t)(v1.x * rs * (1.f + s1.x) + h1.x);
    orow[(tid + 256) * 4 + 1] = (bf16_t)(v1.y * rs * (1.f + s1.y) + h1.y);
    orow[(tid + 256) * 4 + 2] = (bf16_t)(v1.z * rs * (1.f + s1.z) + h1.z);
    orow[(tid + 256) * 4 + 3] = (bf16_t)(v1.w * rs * (1.f + s1.w) + h1.w);
}

// RoPE on q (+ H^-0.5 scale), [BT,NH] bf16 -> [B,N,T,H] bf16
__global__ __launch_bounds__(128)
void rope_q(const bf16_t* __restrict__ qp, const float* __restrict__ positions,
            bf16_t* __restrict__ qo, int T, int NH, int H)
{
    const int t = blockIdx.x, n = blockIdx.y, b = blockIdx.z;
    const int i = threadIdx.x;  // 0..127
    const long in0 = ((long)(b * T + t)) * NH + n * H;
    const float x1 = (float)qp[in0 + i];
    const float x2 = (float)qp[in0 + i + 128];
    const float pos = positions[b * T + t];
    const float inv = expf(-9.210340371976184f * (float)i / 128.f);  // 10000^(-i/128)
    float s, c;
    sincosf(pos * inv, &s, &c);
    const float scl = 0.0625f;  // 256^-0.5
    const long out0 = (((long)(b * 8 + n)) * T + t) * H;
    qo[out0 + i]       = (bf16_t)((x1 * c - x2 * s) * scl);
    qo[out0 + i + 128] = (bf16_t)((x2 * c + x1 * s) * scl);
}

// RoPE on k + transpose v.  kvp: [BT,512] bf16 (cols 0..255 k, 256..511 v)
__global__ __launch_bounds__(128)
void rope_kv(const bf16_t* __restrict__ kvp, const float* __restrict__ positions,
             bf16_t* __restrict__ ko, bf16_t* __restrict__ vt, int T, int H, int S)
{
    const int t = blockIdx.x, b = blockIdx.y;
    const int i = threadIdx.x;  // 0..127
    const long in0 = ((long)(b * T + t)) * 512;
    const float k1 = (float)kvp[in0 + i];
    const float k2 = (float)kvp[in0 + i + 128];
    const float pos = positions[b * T + t];
    const float inv = expf(-9.210340371976184f * (float)i / 128.f);
    float s, c;
    sincosf(pos * inv, &s, &c);
    const long ko0 = ((long)(b * T + t)) * H;
    ko[ko0 + i]       = (bf16_t)(k1 * c - k2 * s);
    ko[ko0 + i + 128] = (bf16_t)(k2 * c + k1 * s);
    // v transpose: vt[b][h][t] = v[b][t][h]
    vt[((long)b * H + i) * S + t]       = kvp[in0 + 256 + i];
    vt[((long)b * H + i + 128) * S + t] = kvp[in0 + 256 + i + 128];
}

// causal mask + softmax over rows of scores [G,T,S] fp32 -> probs bf16
__global__ __launch_bounds__(256)
void softmax_causal(const float* __restrict__ sc, bf16_t* __restrict__ pr, int T, int S)
{
    const int t = blockIdx.x, g = blockIdx.y;
    const long row = (long)g * T + t;
    const float* srow = sc + row * S;
    bf16_t* prow = pr + row * S;
    const int tid = threadIdx.x;
    float vals[8];
    float mx = -3.4e38f;
#pragma unroll
    for (int i = 0; i < 8; i++) {
        const int s = i * 256 + tid;
        const float v = (s <= t) ? srow[s] : -3.4e38f;
        vals[i] = v;
        mx = fmaxf(mx, v);
    }
    for (int o = 32; o; o >>= 1) mx = fmaxf(mx, __shfl_down(mx, o, 64));
    __shared__ float red[4];
    if ((tid & 63) == 0) red[tid >> 6] = mx;
    __syncthreads();
    mx = fmaxf(fmaxf(red[0], red[1]), fmaxf(red[2], red[3]));
    __syncthreads();
    float sum = 0.f;
#pragma unroll
    for (int i = 0; i < 8; i++) {
        const int s = i * 256 + tid;
        const float e = (s <= t) ? __expf(vals[i] - mx) : 0.f;
        vals[i] = e;
        sum += e;
    }
    for (int o = 32; o; o >>= 1) sum += __shfl_down(sum, o, 64);
    if ((tid & 63) == 0) red[tid >> 6] = sum;
    __syncthreads();
    sum = red[0] + red[1] + red[2] + red[3];
    const float invs = 1.f / sum;
#pragma unroll
    for (int i = 0; i < 8; i++)
        prow[i * 256 + tid] = (bf16_t)(vals[i] * invs);
}

extern "C" void kernel_launch(void* const* d_in, const int* in_sizes, int n_in,
                              void* d_out, int out_size, void* d_ws, size_t ws_size,
                              hipStream_t stream)
{
    const float* x      = (const float*)d_in[0];
    const float* pos    = (const float*)d_in[1];
    // d_in[2] = attn_mask: deterministically causal -> folded into softmax kernel
    const float* cond   = (const float*)d_in[3];
    const float* Wmod_a = (const float*)d_in[4];
    const float* bmod_a = (const float*)d_in[5];
    const float* Wq     = (const float*)d_in[6];
    const float* Wkv    = (const float*)d_in[7];
    const float* Wo     = (const float*)d_in[8];
    const float* Wmod_f = (const float*)d_in[9];
    const float* bmod_f = (const float*)d_in[10];
    const float* Wg     = (const float*)d_in[11];
    const float* Wl     = (const float*)d_in[12];

    constexpr int  Bb = 2, T = 2048, D = 2048, F = 16384, Nh = 8, H = 256;
    constexpr int  NH = 2048, S = 2048, G = 8, BT = 4096, D3 = 6144;

    char* ws = (char*)d_ws;
    size_t off = 0;
    auto alloc = [&](size_t bytes) { char* p = ws + off; off += bytes; return p; };

    bf16_t* WQT  = (bf16_t*)alloc((size_t)NH * D * 2);          // [NH, D]
    bf16_t* WKVT = (bf16_t*)alloc((size_t)512 * D * 2);         // [512, D] (k|v)
    bf16_t* WOT  = (bf16_t*)alloc((size_t)D * NH * 2);          // [D, NH]
    bf16_t* WGT  = (bf16_t*)alloc((size_t)2 * F * D * 2);       // [2, F, D]
    bf16_t* WLT  = (bf16_t*)alloc((size_t)D * F * 2);           // [D, F]
    float*  MODA = (float*)alloc((size_t)Bb * D3 * 4);
    float*  MODF = (float*)alloc((size_t)Bb * D3 * 4);
    bf16_t* NA   = (bf16_t*)alloc((size_t)BT * D * 2);
    bf16_t* QP   = (bf16_t*)alloc((size_t)BT * NH * 2);
    bf16_t* KVP  = (bf16_t*)alloc((size_t)BT * 512 * 2);
    bf16_t* Qr   = (bf16_t*)alloc((size_t)Bb * Nh * T * H * 2); // [B,N,T,H]
    bf16_t* Kr   = (bf16_t*)alloc((size_t)Bb * T * H * 2);      // [B,T,H]
    bf16_t* VT   = (bf16_t*)alloc((size_t)Bb * H * S * 2);      // [B,H,S]
    bf16_t* ENC  = (bf16_t*)alloc((size_t)BT * NH * 2);
    float*  X1   = (float*)alloc((size_t)BT * D * 4);
    bf16_t* NF   = (bf16_t*)alloc((size_t)BT * D * 2);
    const size_t scBytes = (size_t)G * T * S * 4;               // per-b scores
    const size_t prBytes = (size_t)G * T * S * 2;
    const size_t hBytes  = (size_t)BT * F * 2;
    const size_t bigBytes = (scBytes + prBytes > hBytes) ? (scBytes + prBytes) : hBytes;
    char* big = alloc(bigBytes);
    float*  SC = (float*)big;
    bf16_t* PR = (bf16_t*)(big + scBytes);
    bf16_t* Hb = (bf16_t*)big;   // aliases SC/PR (attention done before FFN)
    (void)ws_size; (void)in_sizes; (void)n_in; (void)out_size;

    const dim3 tb(32, 8);
    // weight convert+transpose (fp32 -> bf16, B^T layout)
    transpose_f2b<<<dim3(H / 32, D / 32, 8), tb, 0, stream>>>(Wq,  WQT,  D,  H, (long)D * H, (long)H * D);
    transpose_f2b<<<dim3(H / 32, D / 32, 2), tb, 0, stream>>>(Wkv, WKVT, D,  H, (long)D * H, (long)H * D);
    transpose_f2b<<<dim3(D / 32, NH / 32, 1), tb, 0, stream>>>(Wo, WOT, NH,  D, 0, 0);
    transpose_f2b<<<dim3(F / 32, D / 32, 2), tb, 0, stream>>>(Wg,  WGT,  D,  F, (long)D * F, (long)F * D);
    transpose_f2b<<<dim3(D / 32, F / 32, 1), tb, 0, stream>>>(Wl,  WLT,  F,  D, 0, 0);
    // AdaLN modulation vectors
    modk<<<dim3(D3 / 256, Bb), 256, 0, stream>>>(cond, Wmod_a, bmod_a, MODA, D, D3);
    modk<<<dim3(D3 / 256, Bb), 256, 0, stream>>>(cond, Wmod_f, bmod_f, MODF, D, D3);
    // pre-attention RMSNorm
    rmsnorm_adaln<<<BT, 256, 0, stream>>>(x, MODA, NA, D, T, D3);
    // projections
    gemm_bt<EPI_BF16, false><<<dim3(NH / 128, BT / 128, 1), 256, 0, stream>>>(
        NA, WQT, nullptr, QP, BT, NH, D, D, D, NH, 0, 0, 0, nullptr, nullptr, 0, 0);
    gemm_bt<EPI_BF16, false><<<dim3(512 / 128, BT / 128, 1), 256, 0, stream>>>(
        NA, WKVT, nullptr, KVP, BT, 512, D, D, D, 512, 0, 0, 0, nullptr, nullptr, 0, 0);
    // RoPE
    rope_q<<<dim3(T, Nh, Bb), 128, 0, stream>>>(QP, pos, Qr, T, NH, H);
    rope_kv<<<dim3(T, Bb), 128, 0, stream>>>(KVP, pos, Kr, VT, T, H, S);
    // attention, per batch (scores scratch reused)
    for (int b = 0; b < Bb; b++) {
        gemm_bt<EPI_F32, false><<<dim3(S / 128, T / 128, G), 256, 0, stream>>>(
            Qr + (long)b * Nh * T * H, Kr + (long)b * T * H, nullptr, SC,
            T, S, H, H, H, S, (long)T * H, 0, (long)T * S, nullptr, nullptr, 0, 0);
        softmax_causal<<<dim3(T, G), 256, 0, stream>>>(SC, PR, T, S);
        gemm_bt<EPI_BF16, false><<<dim3(H / 128, T / 128, G), 256, 0, stream>>>(
            PR, VT + (long)b * H * S, nullptr, ENC + (long)b * T * NH,
            T, H, S, S, S, NH, (long)T * S, 0, (long)H, nullptr, nullptr, 0, 0);
    }
    // Wo projection + gated residual -> x1
    gemm_bt<EPI_RES, false><<<dim3(D / 128, BT / 128, 1), 256, 0, stream>>>(
        ENC, WOT, nullptr, X1, BT, D, NH, NH, NH, D, 0, 0, 0, x, MODA + 2 * D, D3, T);
    // pre-FFN RMSNorm
    rmsnorm_adaln<<<BT, 256, 0, stream>>>(X1, MODF, NF, D, T, D3);
    // FFN up (dual-B, gelu-gate epilogue) -> h
    gemm_bt<EPI_GELU, true><<<dim3(F / 128, BT / 128, 1), 256, 0, stream>>>(
        NF, WGT, WGT + (long)F * D, Hb, BT, F, D, D, D, F, 0, 0, 0, nullptr, nullptr, 0, 0);
    // FFN down + gated residual -> out
    gemm_bt<EPI_RES, false><<<dim3(D / 128, BT / 128, 1), 256, 0, stream>>>(
        Hb, WLT, nullptr, (float*)d_out, BT, D, F, F, F, D, 0, 0, 0, X1, MODF + 2 * D, D3, T);
}

// Round 2
// 3716.179 us; speedup vs baseline: 1.0960x; 1.0960x over previous
//
#include <hip/hip_runtime.h>
#include <hip/hip_bf16.h>

typedef __bf16 bf16_t;
typedef __bf16 bf16x8 __attribute__((ext_vector_type(8)));
typedef float  f32x4  __attribute__((ext_vector_type(4)));

#define DEV static __device__ __forceinline__

DEV void gload16(const bf16_t* g, bf16_t* l) {
    __builtin_amdgcn_global_load_lds(
        (const __attribute__((address_space(1))) void*)g,
        (__attribute__((address_space(3))) void*)l, 16, 0, 0);
}

enum { EPI_F32 = 0, EPI_BF16 = 1, EPI_RES = 2, EPI_GELU = 3, EPI_MUL = 4 };
// CAUSAL: 0 = none, 1 = skip blocks above diagonal (QK^T), 2 = K-loop limited to m0+128 (PV)

// C = A * Bt^T.  A: [M,Kd] row-major (bf16), Bt: [N,Kd] row-major (bf16).
// 128x128 tile, BK=32, 4 waves (2x2), mfma_f32_16x16x32_bf16.  (m97 structure)
template<int EPI, int CAUSAL>
__global__ __launch_bounds__(256)
void gemm_bt(const bf16_t* __restrict__ A, const bf16_t* __restrict__ Bt,
             void* __restrict__ Cout,
             int M, int N, int Kd, int lda, int ldb, int ldc,
             long sAz, long sBz, long sCz,
             const float* __restrict__ res, const float* __restrict__ gate,
             int gateStride, int rowsPerB, const bf16_t* __restrict__ aux)
{
    const int tid = threadIdx.x;
    const int l   = tid & 63;
    const int w   = tid >> 6;
    const int wr  = w >> 1, wc = w & 1;
    const long m0 = (long)blockIdx.y * 128;
    const long n0 = (long)blockIdx.x * 128;
    const int  z  = blockIdx.z;

    if constexpr (CAUSAL == 1) {
        if (n0 > m0 + 127) return;   // strictly-upper block: softmax never reads it
    }
    int kend = Kd;
    if constexpr (CAUSAL == 2) {
        const int kc = (int)m0 + 128; // probs are zero beyond this row-block's diagonal
        kend = kc < Kd ? kc : Kd;
    }

    A  += (long)z * sAz;
    Bt += (long)z * sBz;

    __shared__ bf16_t As[128 * 32];
    __shared__ bf16_t Bs[128 * 32];

    const int srow = w * 16 + (l >> 2);     // staging row within tile
    const int scol = (l & 3) * 8;           // k-chunk (8 bf16 = 16B)
    const bf16_t* Ag = A  + (m0 + srow) * (long)lda + scol;
    const bf16_t* Bg = Bt + (n0 + srow) * (long)ldb + scol;

    bf16_t* ldsA = As + w * 512;   // wave-uniform base; HW adds lane*16B
    bf16_t* ldsB = Bs + w * 512;

    f32x4 acc[16];
    const f32x4 fz = {0.f, 0.f, 0.f, 0.f};
#pragma unroll
    for (int i = 0; i < 16; i++) acc[i] = fz;

    for (int k0 = 0; k0 < kend; k0 += 32) {
        gload16(Ag + k0,                  ldsA);
        gload16(Ag + k0 + 64 * (long)lda, ldsA + 2048);
        gload16(Bg + k0,                  ldsB);
        gload16(Bg + k0 + 64 * (long)ldb, ldsB + 2048);
        __syncthreads();   // drains vmcnt before barrier

        bf16x8 af[4], bfr[4];
#pragma unroll
        for (int f = 0; f < 4; f++) {
            af[f]  = *(const bf16x8*)(As + (wr * 64 + f * 16 + (l & 15)) * 32 + (l >> 4) * 8);
            bfr[f] = *(const bf16x8*)(Bs + (wc * 64 + f * 16 + (l & 15)) * 32 + (l >> 4) * 8);
        }
#pragma unroll
        for (int i = 0; i < 4; i++)
#pragma unroll
            for (int j = 0; j < 4; j++)
                acc[i * 4 + j] = __builtin_amdgcn_mfma_f32_16x16x32_bf16(af[i], bfr[j], acc[i * 4 + j], 0, 0, 0);
        __syncthreads();
    }

    // epilogue: C/D layout col = lane&15, row = (lane>>4)*4 + reg
#pragma unroll
    for (int i = 0; i < 4; i++) {
#pragma unroll
        for (int j = 0; j < 4; j++) {
            f32x4 v = acc[i * 4 + j];
            const long col  = n0 + wc * 64 + j * 16 + (l & 15);
            const long row0 = m0 + wr * 64 + i * 16 + ((l >> 4) * 4);
#pragma unroll
            for (int e = 0; e < 4; e++) {
                const long row = row0 + e;
                const long idx = row * (long)ldc + col + (long)z * sCz;
                const float val = v[e];
                if constexpr (EPI == EPI_F32) {
                    ((float*)Cout)[idx] = val;
                } else if constexpr (EPI == EPI_BF16) {
                    ((bf16_t*)Cout)[idx] = (bf16_t)val;
                } else if constexpr (EPI == EPI_RES) {
                    const int b = (int)(row / rowsPerB);
                    ((float*)Cout)[idx] = res[row * (long)ldc + col] + val * gate[(long)b * gateStride + col];
                } else if constexpr (EPI == EPI_GELU) {  // gelu(val), tanh approx (JAX default)
                    const float gl = 0.5f * val * (1.f + tanhf(0.7978845608f * (val + 0.044715f * val * val * val)));
                    ((bf16_t*)Cout)[idx] = (bf16_t)gl;
                } else {  // EPI_MUL: out = aux * val (in-place over aux is safe: same idx)
                    ((bf16_t*)Cout)[idx] = (bf16_t)((float)aux[idx] * val);
                }
            }
        }
    }
}

// fp32 [R,C] -> bf16 [C,R] transpose (batched via blockIdx.z)
__global__ __launch_bounds__(256)
void transpose_f2b(const float* __restrict__ in, bf16_t* __restrict__ out,
                   int R, int C, long inStride, long outStride)
{
    __shared__ float tile[32][33];
    in  += (long)blockIdx.z * inStride;
    out += (long)blockIdx.z * outStride;
    const int c0 = blockIdx.x * 32, r0 = blockIdx.y * 32;
    const int tx = threadIdx.x, ty = threadIdx.y;
#pragma unroll
    for (int i = 0; i < 4; i++)
        tile[ty + i * 8][tx] = in[(long)(r0 + ty + i * 8) * C + c0 + tx];
    __syncthreads();
#pragma unroll
    for (int i = 0; i < 4; i++)
        out[(long)(c0 + ty + i * 8) * R + r0 + tx] = (bf16_t)tile[tx][ty + i * 8];
}

// mod = cond @ Wmod + bmod   ([B,D] x [D,3D])
__global__ __launch_bounds__(256)
void modk(const float* __restrict__ cond, const float* __restrict__ W,
          const float* __restrict__ bvec, float* __restrict__ mod, int D, int D3)
{
    const int j = blockIdx.x * 256 + threadIdx.x;
    const int b = blockIdx.y;
    float s = 0.f;
    const float* cb = cond + (long)b * D;
    for (int d = 0; d < D; d++) s += cb[d] * W[(long)d * D3 + j];
    mod[(long)b * D3 + j] = s + bvec[j];
}

// RMSNorm (fp32) + AdaLN scale/shift -> bf16.  One block per row, D=2048.
__global__ __launch_bounds__(256)
void rmsnorm_adaln(const float* __restrict__ xin, const float* __restrict__ mod,
                   bf16_t* __restrict__ out, int D, int T, int D3)
{
    const long row = blockIdx.x;
    const int  b   = (int)(row / T);
    const int  tid = threadIdx.x;
    const float4* x4 = (const float4*)(xin + row * (long)D);
    const float4 v0 = x4[tid], v1 = x4[tid + 256];
    float ss = v0.x * v0.x + v0.y * v0.y + v0.z * v0.z + v0.w * v0.w
             + v1.x * v1.x + v1.y * v1.y + v1.z * v1.z + v1.w * v1.w;
    for (int o = 32; o; o >>= 1) ss += __shfl_down(ss, o, 64);
    __shared__ float red[4];
    if ((tid & 63) == 0) red[tid >> 6] = ss;
    __syncthreads();
    ss = red[0] + red[1] + red[2] + red[3];
    const float rs = rsqrtf(ss / (float)D + 1e-6f);
    const float* sc = mod + (long)b * D3;
    const float* sh = sc + D;
    const float4 s0 = ((const float4*)sc)[tid], s1 = ((const float4*)sc)[tid + 256];
    const float4 h0 = ((const float4*)sh)[tid], h1 = ((const float4*)sh)[tid + 256];
    bf16_t* orow = out + row * (long)D;
    orow[tid * 4 + 0]         = (bf16_t)(v0.x * rs * (1.f + s0.x) + h0.x);
    orow[tid * 4 + 1]         = (bf16_t)(v0.y * rs * (1.f + s0.y) + h0.y);
    orow[tid * 4 + 2]         = (bf16_t)(v0.z * rs * (1.f + s0.z) + h0.z);
    orow[tid * 4 + 3]         = (bf16_t)(v0.w * rs * (1.f + s0.w) + h0.w);
    orow[(tid + 256) * 4 + 0] = (bf16_t)(v1.x * rs * (1.f + s1.x) + h1.x);
    orow[(tid + 256) * 4 + 1] = (bf16_t)(v1.y * rs * (1.f + s1.y) + h1.y);
    orow[(tid + 256) * 4 + 2] = (bf16_t)(v1.z * rs * (1.f + s1.z) + h1.z);
    orow[(tid + 256) * 4 + 3] = (bf16_t)(v1.w * rs * (1.f + s1.w) + h1.w);
}

// RoPE on q (+ H^-0.5 scale), [BT,NH] bf16 -> [B,N,T,H] bf16
__global__ __launch_bounds__(128)
void rope_q(const bf16_t* __restrict__ qp, const float* __restrict__ positions,
            bf16_t* __restrict__ qo, int T, int NH, int H)
{
    const int t = blockIdx.x, n = blockIdx.y, b = blockIdx.z;
    const int i = threadIdx.x;  // 0..127
    const long in0 = ((long)(b * T + t)) * NH + n * H;
    const float x1 = (float)qp[in0 + i];
    const float x2 = (float)qp[in0 + i + 128];
    const float pos = positions[b * T + t];
    const float inv = expf(-9.210340371976184f * (float)i / 128.f);  // 10000^(-i/128)
    float s, c;
    sincosf(pos * inv, &s, &c);
    const float scl = 0.0625f;  // 256^-0.5
    const long out0 = (((long)(b * 8 + n)) * T + t) * H;
    qo[out0 + i]       = (bf16_t)((x1 * c - x2 * s) * scl);
    qo[out0 + i + 128] = (bf16_t)((x2 * c + x1 * s) * scl);
}

// RoPE on k + transpose v.  kvp: [BT,512] bf16 (cols 0..255 k, 256..511 v)
__global__ __launch_bounds__(128)
void rope_kv(const bf16_t* __restrict__ kvp, const float* __restrict__ positions,
             bf16_t* __restrict__ ko, bf16_t* __restrict__ vt, int T, int H, int S)
{
    const int t = blockIdx.x, b = blockIdx.y;
    const int i = threadIdx.x;  // 0..127
    const long in0 = ((long)(b * T + t)) * 512;
    const float k1 = (float)kvp[in0 + i];
    const float k2 = (float)kvp[in0 + i + 128];
    const float pos = positions[b * T + t];
    const float inv = expf(-9.210340371976184f * (float)i / 128.f);
    float s, c;
    sincosf(pos * inv, &s, &c);
    const long ko0 = ((long)(b * T + t)) * H;
    ko[ko0 + i]       = (bf16_t)(k1 * c - k2 * s);
    ko[ko0 + i + 128] = (bf16_t)(k2 * c + k1 * s);
    // v transpose: vt[b][h][t] = v[b][t][h]
    vt[((long)b * H + i) * S + t]       = kvp[in0 + 256 + i];
    vt[((long)b * H + i + 128) * S + t] = kvp[in0 + 256 + i + 128];
}

// causal mask + softmax over rows of scores [G,T,S] fp32 -> probs bf16.
// Only columns [0, t|127] are ever read downstream (PV limits K to the
// diagonal block), so chunks beyond that are skipped entirely.
__global__ __launch_bounds__(256)
void softmax_causal(const float* __restrict__ sc, bf16_t* __restrict__ pr, int T, int S)
{
    const int t = blockIdx.x, g = blockIdx.y;
    const long row = (long)g * T + t;
    const float* srow = sc + row * S;
    bf16_t* prow = pr + row * S;
    const int tid = threadIdx.x;
    const int limit = t | 127;              // last col PV reads for this row
    const int nch = (limit >> 8) + 1;       // 256-wide chunks to process
    float vals[8];
    float mx = -3.4e38f;
    for (int i = 0; i < nch; i++) {
        const int s = i * 256 + tid;
        const float v = (s <= t) ? srow[s] : -3.4e38f;
        vals[i] = v;
        mx = fmaxf(mx, v);
    }
    for (int o = 32; o; o >>= 1) mx = fmaxf(mx, __shfl_down(mx, o, 64));
    __shared__ float red[4];
    if ((tid & 63) == 0) red[tid >> 6] = mx;
    __syncthreads();
    mx = fmaxf(fmaxf(red[0], red[1]), fmaxf(red[2], red[3]));
    __syncthreads();
    float sum = 0.f;
    for (int i = 0; i < nch; i++) {
        const int s = i * 256 + tid;
        const float e = (s <= t) ? __expf(vals[i] - mx) : 0.f;
        vals[i] = e;
        sum += e;
    }
    for (int o = 32; o; o >>= 1) sum += __shfl_down(sum, o, 64);
    if ((tid & 63) == 0) red[tid >> 6] = sum;
    __syncthreads();
    sum = red[0] + red[1] + red[2] + red[3];
    const float invs = 1.f / sum;
    for (int i = 0; i < nch; i++)
        prow[i * 256 + tid] = (bf16_t)(vals[i] * invs);
}

extern "C" void kernel_launch(void* const* d_in, const int* in_sizes, int n_in,
                              void* d_out, int out_size, void* d_ws, size_t ws_size,
                              hipStream_t stream)
{
    const float* x      = (const float*)d_in[0];
    const float* pos    = (const float*)d_in[1];
    // d_in[2] = attn_mask: deterministically causal -> folded into softmax kernel
    const float* cond   = (const float*)d_in[3];
    const float* Wmod_a = (const float*)d_in[4];
    const float* bmod_a = (const float*)d_in[5];
    const float* Wq     = (const float*)d_in[6];
    const float* Wkv    = (const float*)d_in[7];
    const float* Wo     = (const float*)d_in[8];
    const float* Wmod_f = (const float*)d_in[9];
    const float* bmod_f = (const float*)d_in[10];
    const float* Wg     = (const float*)d_in[11];
    const float* Wl     = (const float*)d_in[12];

    constexpr int  Bb = 2, T = 2048, D = 2048, F = 16384, Nh = 8, H = 256;
    constexpr int  NH = 2048, S = 2048, G = 8, BT = 4096, D3 = 6144;

    char* ws = (char*)d_ws;
    size_t off = 0;
    auto alloc = [&](size_t bytes) { char* p = ws + off; off += bytes; return p; };

    bf16_t* WQT  = (bf16_t*)alloc((size_t)NH * D * 2);          // [NH, D]
    bf16_t* WKVT = (bf16_t*)alloc((size_t)512 * D * 2);         // [512, D] (k|v)
    bf16_t* WOT  = (bf16_t*)alloc((size_t)D * NH * 2);          // [D, NH]
    bf16_t* WGT  = (bf16_t*)alloc((size_t)2 * F * D * 2);       // [2, F, D]
    bf16_t* WLT  = (bf16_t*)alloc((size_t)D * F * 2);           // [D, F]
    float*  MODA = (float*)alloc((size_t)Bb * D3 * 4);
    float*  MODF = (float*)alloc((size_t)Bb * D3 * 4);
    bf16_t* NA   = (bf16_t*)alloc((size_t)BT * D * 2);
    bf16_t* QP   = (bf16_t*)alloc((size_t)BT * NH * 2);
    bf16_t* KVP  = (bf16_t*)alloc((size_t)BT * 512 * 2);
    bf16_t* Qr   = (bf16_t*)alloc((size_t)Bb * Nh * T * H * 2); // [B,N,T,H]
    bf16_t* Kr   = (bf16_t*)alloc((size_t)Bb * T * H * 2);      // [B,T,H]
    bf16_t* VT   = (bf16_t*)alloc((size_t)Bb * H * S * 2);      // [B,H,S]
    bf16_t* ENC  = (bf16_t*)alloc((size_t)BT * NH * 2);
    float*  X1   = (float*)alloc((size_t)BT * D * 4);
    bf16_t* NF   = (bf16_t*)alloc((size_t)BT * D * 2);
    const size_t scBytes = (size_t)G * T * S * 4;               // per-b scores
    const size_t prBytes = (size_t)G * T * S * 2;
    const size_t hBytes  = (size_t)BT * F * 2;
    const size_t bigBytes = (scBytes + prBytes > hBytes) ? (scBytes + prBytes) : hBytes;
    char* big = alloc(bigBytes);
    float*  SC = (float*)big;
    bf16_t* PR = (bf16_t*)(big + scBytes);
    bf16_t* Hb = (bf16_t*)big;   // aliases SC/PR (attention done before FFN)
    (void)ws_size; (void)in_sizes; (void)n_in; (void)out_size;

    const dim3 tb(32, 8);
    // weight convert+transpose (fp32 -> bf16, B^T layout)
    transpose_f2b<<<dim3(H / 32, D / 32, 8), tb, 0, stream>>>(Wq,  WQT,  D,  H, (long)D * H, (long)H * D);
    transpose_f2b<<<dim3(H / 32, D / 32, 2), tb, 0, stream>>>(Wkv, WKVT, D,  H, (long)D * H, (long)H * D);
    transpose_f2b<<<dim3(D / 32, NH / 32, 1), tb, 0, stream>>>(Wo, WOT, NH,  D, 0, 0);
    transpose_f2b<<<dim3(F / 32, D / 32, 2), tb, 0, stream>>>(Wg,  WGT,  D,  F, (long)D * F, (long)F * D);
    transpose_f2b<<<dim3(D / 32, F / 32, 1), tb, 0, stream>>>(Wl,  WLT,  F,  D, 0, 0);
    // AdaLN modulation vectors
    modk<<<dim3(D3 / 256, Bb), 256, 0, stream>>>(cond, Wmod_a, bmod_a, MODA, D, D3);
    modk<<<dim3(D3 / 256, Bb), 256, 0, stream>>>(cond, Wmod_f, bmod_f, MODF, D, D3);
    // pre-attention RMSNorm
    rmsnorm_adaln<<<BT, 256, 0, stream>>>(x, MODA, NA, D, T, D3);
    // projections
    gemm_bt<EPI_BF16, 0><<<dim3(NH / 128, BT / 128, 1), 256, 0, stream>>>(
        NA, WQT, QP, BT, NH, D, D, D, NH, 0, 0, 0, nullptr, nullptr, 0, 0, nullptr);
    gemm_bt<EPI_BF16, 0><<<dim3(512 / 128, BT / 128, 1), 256, 0, stream>>>(
        NA, WKVT, KVP, BT, 512, D, D, D, 512, 0, 0, 0, nullptr, nullptr, 0, 0, nullptr);
    // RoPE
    rope_q<<<dim3(T, Nh, Bb), 128, 0, stream>>>(QP, pos, Qr, T, NH, H);
    rope_kv<<<dim3(T, Bb), 128, 0, stream>>>(KVP, pos, Kr, VT, T, H, S);
    // attention, per batch (scores scratch reused)
    for (int b = 0; b < Bb; b++) {
        gemm_bt<EPI_F32, 1><<<dim3(S / 128, T / 128, G), 256, 0, stream>>>(
            Qr + (long)b * Nh * T * H, Kr + (long)b * T * H, SC,
            T, S, H, H, H, S, (long)T * H, 0, (long)T * S, nullptr, nullptr, 0, 0, nullptr);
        softmax_causal<<<dim3(T, G), 256, 0, stream>>>(SC, PR, T, S);
        gemm_bt<EPI_BF16, 2><<<dim3(H / 128, T / 128, G), 256, 0, stream>>>(
            PR, VT + (long)b * H * S, ENC + (long)b * T * NH,
            T, H, S, S, S, NH, (long)T * S, 0, (long)H, nullptr, nullptr, 0, 0, nullptr);
    }
    // Wo projection + gated residual -> x1
    gemm_bt<EPI_RES, 0><<<dim3(D / 128, BT / 128, 1), 256, 0, stream>>>(
        ENC, WOT, X1, BT, D, NH, NH, NH, D, 0, 0, 0, x, MODA + 2 * D, D3, T, nullptr);
    // pre-FFN RMSNorm
    rmsnorm_adaln<<<BT, 256, 0, stream>>>(X1, MODF, NF, D, T, D3);
    // FFN up, two single-B GEMMs: h0 = gelu(n@Wg0); h = h0 * (n@Wg1) in-place
    gemm_bt<EPI_GELU, 0><<<dim3(F / 128, BT / 128, 1), 256, 0, stream>>>(
        NF, WGT, Hb, BT, F, D, D, D, F, 0, 0, 0, nullptr, nullptr, 0, 0, nullptr);
    gemm_bt<EPI_MUL, 0><<<dim3(F / 128, BT / 128, 1), 256, 0, stream>>>(
        NF, WGT + (long)F * D, Hb, BT, F, D, D, D, F, 0, 0, 0, nullptr, nullptr, 0, 0, Hb);
    // FFN down + gated residual -> out
    gemm_bt<EPI_RES, 0><<<dim3(D / 128, BT / 128, 1), 256, 0, stream>>>(
        Hb, WLT, (float*)d_out, BT, D, F, F, F, D, 0, 0, 0, X1, MODF + 2 * D, D3, T, nullptr);
}

// Round 3
// 2098.826 us; speedup vs baseline: 1.9405x; 1.7706x over previous
//
#include <hip/hip_runtime.h>
#include <hip/hip_bf16.h>

typedef __bf16 bf16_t;
typedef __bf16 bf16x8 __attribute__((ext_vector_type(8)));
typedef float  f32x4  __attribute__((ext_vector_type(4)));

#define DEV static __device__ __forceinline__

DEV void gload16(const bf16_t* g, bf16_t* l) {
    __builtin_amdgcn_global_load_lds(
        (const __attribute__((address_space(1))) void*)g,
        (__attribute__((address_space(3))) void*)l, 16, 0, 0);
}

enum { EPI_F32 = 0, EPI_BF16 = 1, EPI_RES = 2, EPI_GELU = 3, EPI_MUL = 4 };
// CAUSAL: 0 = none, 1 = skip blocks above diagonal (QK^T), 2 = K-loop limited to m0+128 (PV)

// C = A * Bt^T.  A: [M,Kd] row-major (bf16), Bt: [N,Kd] row-major (bf16).
// 128x128 tile, BK=32, 4 waves (2x2), mfma_f32_16x16x32_bf16.  (m97 structure)
template<int EPI, int CAUSAL>
__global__ __launch_bounds__(256)
void gemm_bt(const bf16_t* __restrict__ A, const bf16_t* __restrict__ Bt,
             void* __restrict__ Cout,
             int M, int N, int Kd, int lda, int ldb, int ldc,
             long sAz, long sBz, long sCz,
             const float* __restrict__ res, const float* __restrict__ gate,
             int gateStride, int rowsPerB, const bf16_t* __restrict__ aux)
{
    const int tid = threadIdx.x;
    const int l   = tid & 63;
    const int w   = tid >> 6;
    const int wr  = w >> 1, wc = w & 1;
    const long m0 = (long)blockIdx.y * 128;
    const long n0 = (long)blockIdx.x * 128;
    const int  z  = blockIdx.z;

    if constexpr (CAUSAL == 1) {
        if (n0 > m0 + 127) return;   // strictly-upper block: softmax never reads it
    }
    int kend = Kd;
    if constexpr (CAUSAL == 2) {
        const int kc = (int)m0 + 128; // probs are zero beyond this row-block's diagonal
        kend = kc < Kd ? kc : Kd;
    }

    A  += (long)z * sAz;
    Bt += (long)z * sBz;

    __shared__ bf16_t As[128 * 32];
    __shared__ bf16_t Bs[128 * 32];

    const int srow = w * 16 + (l >> 2);     // staging row within tile
    const int scol = (l & 3) * 8;           // k-chunk (8 bf16 = 16B)
    const bf16_t* Ag = A  + (m0 + srow) * (long)lda + scol;
    const bf16_t* Bg = Bt + (n0 + srow) * (long)ldb + scol;

    bf16_t* ldsA = As + w * 512;   // wave-uniform base; HW adds lane*16B
    bf16_t* ldsB = Bs + w * 512;

    f32x4 acc[16];
    const f32x4 fz = {0.f, 0.f, 0.f, 0.f};
#pragma unroll
    for (int i = 0; i < 16; i++) acc[i] = fz;

    for (int k0 = 0; k0 < kend; k0 += 32) {
        gload16(Ag + k0,                  ldsA);
        gload16(Ag + k0 + 64 * (long)lda, ldsA + 2048);
        gload16(Bg + k0,                  ldsB);
        gload16(Bg + k0 + 64 * (long)ldb, ldsB + 2048);
        __syncthreads();   // drains vmcnt before barrier

        bf16x8 af[4], bfr[4];
#pragma unroll
        for (int f = 0; f < 4; f++) {
            af[f]  = *(const bf16x8*)(As + (wr * 64 + f * 16 + (l & 15)) * 32 + (l >> 4) * 8);
            bfr[f] = *(const bf16x8*)(Bs + (wc * 64 + f * 16 + (l & 15)) * 32 + (l >> 4) * 8);
        }
#pragma unroll
        for (int i = 0; i < 4; i++)
#pragma unroll
            for (int j = 0; j < 4; j++)
                acc[i * 4 + j] = __builtin_amdgcn_mfma_f32_16x16x32_bf16(af[i], bfr[j], acc[i * 4 + j], 0, 0, 0);
        __syncthreads();
    }

    // epilogue: C/D layout col = lane&15, row = (lane>>4)*4 + reg
#pragma unroll
    for (int i = 0; i < 4; i++) {
#pragma unroll
        for (int j = 0; j < 4; j++) {
            f32x4 v = acc[i * 4 + j];
            const long col  = n0 + wc * 64 + j * 16 + (l & 15);
            const long row0 = m0 + wr * 64 + i * 16 + ((l >> 4) * 4);
#pragma unroll
            for (int e = 0; e < 4; e++) {
                const long row = row0 + e;
                const long idx = row * (long)ldc + col + (long)z * sCz;
                const float val = v[e];
                if constexpr (EPI == EPI_F32) {
                    ((float*)Cout)[idx] = val;
                } else if constexpr (EPI == EPI_BF16) {
                    ((bf16_t*)Cout)[idx] = (bf16_t)val;
                } else if constexpr (EPI == EPI_RES) {
                    const int b = (int)(row / rowsPerB);
                    ((float*)Cout)[idx] = res[row * (long)ldc + col] + val * gate[(long)b * gateStride + col];
                } else if constexpr (EPI == EPI_GELU) {  // gelu(val), tanh approx (JAX default)
                    const float gl = 0.5f * val * (1.f + tanhf(0.7978845608f * (val + 0.044715f * val * val * val)));
                    ((bf16_t*)Cout)[idx] = (bf16_t)gl;
                } else {  // EPI_MUL: out = aux * val (in-place over aux is safe: same idx)
                    ((bf16_t*)Cout)[idx] = (bf16_t)((float)aux[idx] * val);
                }
            }
        }
    }
}

// fp32 [R,C] -> bf16 [C,R] transpose (batched via blockIdx.z)
__global__ __launch_bounds__(256)
void transpose_f2b(const float* __restrict__ in, bf16_t* __restrict__ out,
                   int R, int C, long inStride, long outStride)
{
    __shared__ float tile[32][33];
    in  += (long)blockIdx.z * inStride;
    out += (long)blockIdx.z * outStride;
    const int c0 = blockIdx.x * 32, r0 = blockIdx.y * 32;
    const int tx = threadIdx.x, ty = threadIdx.y;
#pragma unroll
    for (int i = 0; i < 4; i++)
        tile[ty + i * 8][tx] = in[(long)(r0 + ty + i * 8) * C + c0 + tx];
    __syncthreads();
#pragma unroll
    for (int i = 0; i < 4; i++)
        out[(long)(c0 + ty + i * 8) * R + r0 + tx] = (bf16_t)tile[tx][ty + i * 8];
}

// mod = cond @ Wmod + bmod, two-stage K-split (deterministic, no atomics).
// Stage 1: partial[z][b][j] = sum_{d in slice z} cond[b][d] * W[d][j]
__global__ __launch_bounds__(256)
void modk_part(const float* __restrict__ cond, const float* __restrict__ W,
               float* __restrict__ part, int D3, int KS)
{
    const int j = blockIdx.x * 256 + threadIdx.x;
    const int b = blockIdx.y;
    const int z = blockIdx.z;
    const float* cb = cond + (long)b * (KS * gridDim.z);
    float s = 0.f;
    const int d0 = z * KS;
#pragma unroll 4
    for (int d = d0; d < d0 + KS; d++) s += cb[d] * W[(long)d * D3 + j];
    part[((long)z * gridDim.y + b) * D3 + j] = s;
}

// Stage 2: mod[b][j] = bias[j] + sum_z partial[z][b][j]
__global__ __launch_bounds__(256)
void modk_reduce(const float* __restrict__ part, const float* __restrict__ bvec,
                 float* __restrict__ mod, int D3, int NZ)
{
    const int j = blockIdx.x * 256 + threadIdx.x;
    const int b = blockIdx.y;
    float s = bvec[j];
    for (int z = 0; z < NZ; z++) s += part[((long)z * gridDim.y + b) * D3 + j];
    mod[(long)b * D3 + j] = s;
}

// RMSNorm (fp32) + AdaLN scale/shift -> bf16.  One block per row, D=2048.
__global__ __launch_bounds__(256)
void rmsnorm_adaln(const float* __restrict__ xin, const float* __restrict__ mod,
                   bf16_t* __restrict__ out, int D, int T, int D3)
{
    const long row = blockIdx.x;
    const int  b   = (int)(row / T);
    const int  tid = threadIdx.x;
    const float4* x4 = (const float4*)(xin + row * (long)D);
    const float4 v0 = x4[tid], v1 = x4[tid + 256];
    float ss = v0.x * v0.x + v0.y * v0.y + v0.z * v0.z + v0.w * v0.w
             + v1.x * v1.x + v1.y * v1.y + v1.z * v1.z + v1.w * v1.w;
    for (int o = 32; o; o >>= 1) ss += __shfl_down(ss, o, 64);
    __shared__ float red[4];
    if ((tid & 63) == 0) red[tid >> 6] = ss;
    __syncthreads();
    ss = red[0] + red[1] + red[2] + red[3];
    const float rs = rsqrtf(ss / (float)D + 1e-6f);
    const float* sc = mod + (long)b * D3;
    const float* sh = sc + D;
    const float4 s0 = ((const float4*)sc)[tid], s1 = ((const float4*)sc)[tid + 256];
    const float4 h0 = ((const float4*)sh)[tid], h1 = ((const float4*)sh)[tid + 256];
    bf16_t* orow = out + row * (long)D;
    orow[tid * 4 + 0]         = (bf16_t)(v0.x * rs * (1.f + s0.x) + h0.x);
    orow[tid * 4 + 1]         = (bf16_t)(v0.y * rs * (1.f + s0.y) + h0.y);
    orow[tid * 4 + 2]         = (bf16_t)(v0.z * rs * (1.f + s0.z) + h0.z);
    orow[tid * 4 + 3]         = (bf16_t)(v0.w * rs * (1.f + s0.w) + h0.w);
    orow[(tid + 256) * 4 + 0] = (bf16_t)(v1.x * rs * (1.f + s1.x) + h1.x);
    orow[(tid + 256) * 4 + 1] = (bf16_t)(v1.y * rs * (1.f + s1.y) + h1.y);
    orow[(tid + 256) * 4 + 2] = (bf16_t)(v1.z * rs * (1.f + s1.z) + h1.z);
    orow[(tid + 256) * 4 + 3] = (bf16_t)(v1.w * rs * (1.f + s1.w) + h1.w);
}

// RoPE on q (+ H^-0.5 scale), [BT,NH] bf16 -> [B,N,T,H] bf16
__global__ __launch_bounds__(128)
void rope_q(const bf16_t* __restrict__ qp, const float* __restrict__ positions,
            bf16_t* __restrict__ qo, int T, int NH, int H)
{
    const int t = blockIdx.x, n = blockIdx.y, b = blockIdx.z;
    const int i = threadIdx.x;  // 0..127
    const long in0 = ((long)(b * T + t)) * NH + n * H;
    const float x1 = (float)qp[in0 + i];
    const float x2 = (float)qp[in0 + i + 128];
    const float pos = positions[b * T + t];
    const float inv = expf(-9.210340371976184f * (float)i / 128.f);  // 10000^(-i/128)
    float s, c;
    sincosf(pos * inv, &s, &c);
    const float scl = 0.0625f;  // 256^-0.5
    const long out0 = (((long)(b * 8 + n)) * T + t) * H;
    qo[out0 + i]       = (bf16_t)((x1 * c - x2 * s) * scl);
    qo[out0 + i + 128] = (bf16_t)((x2 * c + x1 * s) * scl);
}

// RoPE on k + transpose v.  kvp: [BT,512] bf16 (cols 0..255 k, 256..511 v)
__global__ __launch_bounds__(128)
void rope_kv(const bf16_t* __restrict__ kvp, const float* __restrict__ positions,
             bf16_t* __restrict__ ko, bf16_t* __restrict__ vt, int T, int H, int S)
{
    const int t = blockIdx.x, b = blockIdx.y;
    const int i = threadIdx.x;  // 0..127
    const long in0 = ((long)(b * T + t)) * 512;
    const float k1 = (float)kvp[in0 + i];
    const float k2 = (float)kvp[in0 + i + 128];
    const float pos = positions[b * T + t];
    const float inv = expf(-9.210340371976184f * (float)i / 128.f);
    float s, c;
    sincosf(pos * inv, &s, &c);
    const long ko0 = ((long)(b * T + t)) * H;
    ko[ko0 + i]       = (bf16_t)(k1 * c - k2 * s);
    ko[ko0 + i + 128] = (bf16_t)(k2 * c + k1 * s);
    // v transpose: vt[b][h][t] = v[b][t][h]
    vt[((long)b * H + i) * S + t]       = kvp[in0 + 256 + i];
    vt[((long)b * H + i + 128) * S + t] = kvp[in0 + 256 + i + 128];
}

// causal mask + softmax over rows of scores [G,T,S] fp32 -> probs bf16.
// Only columns [0, t|127] are ever read downstream (PV limits K to the
// diagonal block), so chunks beyond that are skipped entirely.
__global__ __launch_bounds__(256)
void softmax_causal(const float* __restrict__ sc, bf16_t* __restrict__ pr, int T, int S)
{
    const int t = blockIdx.x, g = blockIdx.y;
    const long row = (long)g * T + t;
    const float* srow = sc + row * S;
    bf16_t* prow = pr + row * S;
    const int tid = threadIdx.x;
    const int limit = t | 127;              // last col PV reads for this row
    const int nch = (limit >> 8) + 1;       // 256-wide chunks to process
    float vals[8];
    float mx = -3.4e38f;
    for (int i = 0; i < nch; i++) {
        const int s = i * 256 + tid;
        const float v = (s <= t) ? srow[s] : -3.4e38f;
        vals[i] = v;
        mx = fmaxf(mx, v);
    }
    for (int o = 32; o; o >>= 1) mx = fmaxf(mx, __shfl_down(mx, o, 64));
    __shared__ float red[4];
    if ((tid & 63) == 0) red[tid >> 6] = mx;
    __syncthreads();
    mx = fmaxf(fmaxf(red[0], red[1]), fmaxf(red[2], red[3]));
    __syncthreads();
    float sum = 0.f;
    for (int i = 0; i < nch; i++) {
        const int s = i * 256 + tid;
        const float e = (s <= t) ? __expf(vals[i] - mx) : 0.f;
        vals[i] = e;
        sum += e;
    }
    for (int o = 32; o; o >>= 1) sum += __shfl_down(sum, o, 64);
    if ((tid & 63) == 0) red[tid >> 6] = sum;
    __syncthreads();
    sum = red[0] + red[1] + red[2] + red[3];
    const float invs = 1.f / sum;
    for (int i = 0; i < nch; i++)
        prow[i * 256 + tid] = (bf16_t)(vals[i] * invs);
}

extern "C" void kernel_launch(void* const* d_in, const int* in_sizes, int n_in,
                              void* d_out, int out_size, void* d_ws, size_t ws_size,
                              hipStream_t stream)
{
    const float* x      = (const float*)d_in[0];
    const float* pos    = (const float*)d_in[1];
    // d_in[2] = attn_mask: deterministically causal -> folded into softmax kernel
    const float* cond   = (const float*)d_in[3];
    const float* Wmod_a = (const float*)d_in[4];
    const float* bmod_a = (const float*)d_in[5];
    const float* Wq     = (const float*)d_in[6];
    const float* Wkv    = (const float*)d_in[7];
    const float* Wo     = (const float*)d_in[8];
    const float* Wmod_f = (const float*)d_in[9];
    const float* bmod_f = (const float*)d_in[10];
    const float* Wg     = (const float*)d_in[11];
    const float* Wl     = (const float*)d_in[12];

    constexpr int  Bb = 2, T = 2048, D = 2048, F = 16384, Nh = 8, H = 256;
    constexpr int  NH = 2048, S = 2048, G = 8, BT = 4096, D3 = 6144;
    constexpr int  KSLICE = 64, NZ = D / KSLICE;   // 32 K-slices for modk

    char* ws = (char*)d_ws;
    size_t off = 0;
    auto alloc = [&](size_t bytes) { char* p = ws + off; off += bytes; return p; };

    bf16_t* WQT  = (bf16_t*)alloc((size_t)NH * D * 2);          // [NH, D]
    bf16_t* WKVT = (bf16_t*)alloc((size_t)512 * D * 2);         // [512, D] (k|v)
    bf16_t* WOT  = (bf16_t*)alloc((size_t)D * NH * 2);          // [D, NH]
    bf16_t* WGT  = (bf16_t*)alloc((size_t)2 * F * D * 2);       // [2, F, D]
    bf16_t* WLT  = (bf16_t*)alloc((size_t)D * F * 2);           // [D, F]
    float*  MODA = (float*)alloc((size_t)Bb * D3 * 4);
    float*  MODF = (float*)alloc((size_t)Bb * D3 * 4);
    float*  PART = (float*)alloc((size_t)NZ * Bb * D3 * 4);     // modk partials
    bf16_t* NA   = (bf16_t*)alloc((size_t)BT * D * 2);
    bf16_t* QP   = (bf16_t*)alloc((size_t)BT * NH * 2);
    bf16_t* KVP  = (bf16_t*)alloc((size_t)BT * 512 * 2);
    bf16_t* Qr   = (bf16_t*)alloc((size_t)Bb * Nh * T * H * 2); // [B,N,T,H]
    bf16_t* Kr   = (bf16_t*)alloc((size_t)Bb * T * H * 2);      // [B,T,H]
    bf16_t* VT   = (bf16_t*)alloc((size_t)Bb * H * S * 2);      // [B,H,S]
    bf16_t* ENC  = (bf16_t*)alloc((size_t)BT * NH * 2);
    float*  X1   = (float*)alloc((size_t)BT * D * 4);
    bf16_t* NF   = (bf16_t*)alloc((size_t)BT * D * 2);
    const size_t scBytes = (size_t)G * T * S * 4;               // per-b scores
    const size_t prBytes = (size_t)G * T * S * 2;
    const size_t hBytes  = (size_t)BT * F * 2;
    const size_t bigBytes = (scBytes + prBytes > hBytes) ? (scBytes + prBytes) : hBytes;
    char* big = alloc(bigBytes);
    float*  SC = (float*)big;
    bf16_t* PR = (bf16_t*)(big + scBytes);
    bf16_t* Hb = (bf16_t*)big;   // aliases SC/PR (attention done before FFN)
    (void)ws_size; (void)in_sizes; (void)n_in; (void)out_size;

    const dim3 tb(32, 8);
    // weight convert+transpose (fp32 -> bf16, B^T layout)
    transpose_f2b<<<dim3(H / 32, D / 32, 8), tb, 0, stream>>>(Wq,  WQT,  D,  H, (long)D * H, (long)H * D);
    transpose_f2b<<<dim3(H / 32, D / 32, 2), tb, 0, stream>>>(Wkv, WKVT, D,  H, (long)D * H, (long)H * D);
    transpose_f2b<<<dim3(D / 32, NH / 32, 1), tb, 0, stream>>>(Wo, WOT, NH,  D, 0, 0);
    transpose_f2b<<<dim3(F / 32, D / 32, 2), tb, 0, stream>>>(Wg,  WGT,  D,  F, (long)D * F, (long)F * D);
    transpose_f2b<<<dim3(D / 32, F / 32, 1), tb, 0, stream>>>(Wl,  WLT,  F,  D, 0, 0);
    // AdaLN modulation vectors (two-stage K-split)
    modk_part<<<dim3(D3 / 256, Bb, NZ), 256, 0, stream>>>(cond, Wmod_a, PART, D3, KSLICE);
    modk_reduce<<<dim3(D3 / 256, Bb), 256, 0, stream>>>(PART, bmod_a, MODA, D3, NZ);
    modk_part<<<dim3(D3 / 256, Bb, NZ), 256, 0, stream>>>(cond, Wmod_f, PART, D3, KSLICE);
    modk_reduce<<<dim3(D3 / 256, Bb), 256, 0, stream>>>(PART, bmod_f, MODF, D3, NZ);
    // pre-attention RMSNorm
    rmsnorm_adaln<<<BT, 256, 0, stream>>>(x, MODA, NA, D, T, D3);
    // projections
    gemm_bt<EPI_BF16, 0><<<dim3(NH / 128, BT / 128, 1), 256, 0, stream>>>(
        NA, WQT, QP, BT, NH, D, D, D, NH, 0, 0, 0, nullptr, nullptr, 0, 0, nullptr);
    gemm_bt<EPI_BF16, 0><<<dim3(512 / 128, BT / 128, 1), 256, 0, stream>>>(
        NA, WKVT, KVP, BT, 512, D, D, D, 512, 0, 0, 0, nullptr, nullptr, 0, 0, nullptr);
    // RoPE
    rope_q<<<dim3(T, Nh, Bb), 128, 0, stream>>>(QP, pos, Qr, T, NH, H);
    rope_kv<<<dim3(T, Bb), 128, 0, stream>>>(KVP, pos, Kr, VT, T, H, S);
    // attention, per batch (scores scratch reused)
    for (int b = 0; b < Bb; b++) {
        gemm_bt<EPI_F32, 1><<<dim3(S / 128, T / 128, G), 256, 0, stream>>>(
            Qr + (long)b * Nh * T * H, Kr + (long)b * T * H, SC,
            T, S, H, H, H, S, (long)T * H, 0, (long)T * S, nullptr, nullptr, 0, 0, nullptr);
        softmax_causal<<<dim3(T, G), 256, 0, stream>>>(SC, PR, T, S);
        gemm_bt<EPI_BF16, 2><<<dim3(H / 128, T / 128, G), 256, 0, stream>>>(
            PR, VT + (long)b * H * S, ENC + (long)b * T * NH,
            T, H, S, S, S, NH, (long)T * S, 0, (long)H, nullptr, nullptr, 0, 0, nullptr);
    }
    // Wo projection + gated residual -> x1
    gemm_bt<EPI_RES, 0><<<dim3(D / 128, BT / 128, 1), 256, 0, stream>>>(
        ENC, WOT, X1, BT, D, NH, NH, NH, D, 0, 0, 0, x, MODA + 2 * D, D3, T, nullptr);
    // pre-FFN RMSNorm
    rmsnorm_adaln<<<BT, 256, 0, stream>>>(X1, MODF, NF, D, T, D3);
    // FFN up, two single-B GEMMs: h0 = gelu(n@Wg0); h = h0 * (n@Wg1) in-place
    gemm_bt<EPI_GELU, 0><<<dim3(F / 128, BT / 128, 1), 256, 0, stream>>>(
        NF, WGT, Hb, BT, F, D, D, D, F, 0, 0, 0, nullptr, nullptr, 0, 0, nullptr);
    gemm_bt<EPI_MUL, 0><<<dim3(F / 128, BT / 128, 1), 256, 0, stream>>>(
        NF, WGT + (long)F * D, Hb, BT, F, D, D, D, F, 0, 0, 0, nullptr, nullptr, 0, 0, Hb);
    // FFN down + gated residual -> out
    gemm_bt<EPI_RES, 0><<<dim3(D / 128, BT / 128, 1), 256, 0, stream>>>(
        Hb, WLT, (float*)d_out, BT, D, F, F, F, D, 0, 0, 0, X1, MODF + 2 * D, D3, T, nullptr);
}

// Round 4
// 1997.969 us; speedup vs baseline: 2.0385x; 1.0505x over previous
//
#include <hip/hip_runtime.h>
#include <hip/hip_bf16.h>

typedef __bf16 bf16_t;
typedef __bf16 bf16x8 __attribute__((ext_vector_type(8)));
typedef float  f32x4  __attribute__((ext_vector_type(4)));

#define DEV static __device__ __forceinline__

DEV void gload16(const bf16_t* g, bf16_t* l) {
    __builtin_amdgcn_global_load_lds(
        (const __attribute__((address_space(1))) void*)g,
        (__attribute__((address_space(3))) void*)l, 16, 0, 0);
}

enum { EPI_F32 = 0, EPI_BF16 = 1, EPI_RES = 2, EPI_GELU = 3, EPI_MUL = 4 };

#define BARRIER() __builtin_amdgcn_s_barrier()
#define WVM8() asm volatile("s_waitcnt vmcnt(8)" ::: "memory")
#define WVM4() asm volatile("s_waitcnt vmcnt(4)" ::: "memory")
#define WVM0() asm volatile("s_waitcnt vmcnt(0)" ::: "memory")
#define WLG0() asm volatile("s_waitcnt lgkmcnt(0)" ::: "memory")

// ---------------------------------------------------------------------------
// 256x256-tile, BK=64, 8-wave (2Mx4N), 4-phase-per-K-tile GEMM (8-phase/2tiles
// template: T2 swizzle + T3/T4 counted vmcnt + T5 setprio).
// C = A * Bt^T. A:[M,Kd] bf16 row-major, Bt:[N,Kd] bf16 row-major.
// Requires: M,N multiples of 256; Kd multiple of 64; Kd/64 >= 3.
// LDS layout per buffer: [kh][256 rows][32 cols], chunk-swizzled:
//   LDS(row, chunk c) holds global k-chunk (c ^ (row&3))  (16B chunks)
// Staged via linear global_load_lds with pre-swizzled per-lane global source.
// ---------------------------------------------------------------------------
#define G256_PHASE(KS, MH, STAGE_STMT, WAIT_STMT)                          \
  {                                                                        \
    bf16x8 af[4], bfv[4];                                                  \
    _Pragma("unroll")                                                      \
    for (int i = 0; i < 4; i++) {                                          \
      const int arow = wr*128 + MH*64 + i*16 + (l & 15);                   \
      af[i]  = *(const bf16x8*)(&sAc[KS*8192 + arow*32 + csr]);            \
      const int brow = wcn*64 + i*16 + (l & 15);                           \
      bfv[i] = *(const bf16x8*)(&sBc[KS*8192 + brow*32 + csr]);            \
    }                                                                      \
    STAGE_STMT;                                                            \
    BARRIER();                                                             \
    WLG0();                                                                \
    __builtin_amdgcn_sched_barrier(0);                                     \
    __builtin_amdgcn_s_setprio(1);                                         \
    _Pragma("unroll")                                                      \
    for (int i = 0; i < 4; i++)                                            \
      _Pragma("unroll")                                                    \
      for (int j = 0; j < 4; j++)                                          \
        acc[MH*4+i][j] = __builtin_amdgcn_mfma_f32_16x16x32_bf16(          \
            af[i], bfv[j], acc[MH*4+i][j], 0, 0, 0);                       \
    __builtin_amdgcn_s_setprio(0);                                         \
    WAIT_STMT;                                                             \
    BARRIER();                                                             \
  }

template<int EPI>
__global__ __launch_bounds__(512, 1)
void gemm256(const bf16_t* __restrict__ A, const bf16_t* __restrict__ Bt,
             void* __restrict__ Cout, int Kd, int lda, int ldb, int ldc,
             const float* __restrict__ res, const float* __restrict__ gate,
             int gateStride, int rowsPerB, const bf16_t* __restrict__ aux)
{
    const int nbx = gridDim.x;
    const int nwg = nbx * gridDim.y;
    int lin = blockIdx.y * nbx + blockIdx.x;
    // bijective XCD-chunked swizzle (m204)
    const int q8 = nwg >> 3, r8 = nwg & 7;
    const int xcd = lin & 7, oo = lin >> 3;
    lin = (xcd < r8 ? xcd * (q8 + 1) : r8 * (q8 + 1) + (xcd - r8) * q8) + oo;
    const long m0 = (long)(lin / nbx) * 256;
    const long n0 = (long)(lin % nbx) * 256;

    const int tid = threadIdx.x;
    const int l   = tid & 63;
    const int w   = tid >> 6;     // 0..7
    const int wr  = w >> 2;       // 0..1 (M half)
    const int wcn = w & 3;        // 0..3 (N quarter)

    __shared__ bf16_t sA[2][16384];
    __shared__ bf16_t sB[2][16384];

    const int rsub = tid >> 2;                                // stage row (L adds 128)
    const long cs8 = (long)(((l & 3) ^ ((l >> 2) & 3)) << 3); // stage col swizzle (elems)
    const int csr  = (((l >> 4) ^ (l & 3)) << 3);             // read chunk swizzle (elems)

    const int NT = Kd >> 6;

    auto STAGE = [&](const bf16_t* __restrict__ G, long row0, int ld, long kc0, bf16_t* lb) {
#pragma unroll
        for (int L = 0; L < 2; L++) {
            const long g = (row0 + L * 128 + rsub) * (long)ld + kc0 + cs8;
            gload16(G + g, lb + L * 4096 + w * 512);
        }
    };

    f32x4 acc[8][4];
#pragma unroll
    for (int i = 0; i < 8; i++)
#pragma unroll
        for (int j = 0; j < 4; j++) acc[i][j] = f32x4{0.f, 0.f, 0.f, 0.f};

    // prologue: 6 halves (tile0 kh0, tile0 kh1, tile1 kh0)
    STAGE(A,  m0, lda, 0,  &sA[0][0]);
    STAGE(Bt, n0, ldb, 0,  &sB[0][0]);
    STAGE(A,  m0, lda, 32, &sA[0][8192]);
    STAGE(Bt, n0, ldb, 32, &sB[0][8192]);
    STAGE(A,  m0, lda, 64, &sA[1][0]);
    STAGE(Bt, n0, ldb, 64, &sB[1][0]);
    WVM8();       // tile0 kh0 (A,B) resident
    BARRIER();

    for (int t = 0; t < NT; ++t) {
        const int cur = t & 1;
        bf16_t* sAc = sA[cur];
        bf16_t* sBc = sB[cur];

        G256_PHASE(0, 0,
            { if (t + 1 < NT) STAGE(A,  m0, lda, (long)(t + 1) * 64 + 32, &sA[(t + 1) & 1][8192]); },
            { })
        G256_PHASE(0, 1,
            { if (t + 1 < NT) STAGE(Bt, n0, ldb, (long)(t + 1) * 64 + 32, &sB[(t + 1) & 1][8192]); },
            { if (t < NT - 1) { WVM8(); } else { WVM0(); } })   // cur-tile kh1 resident
        G256_PHASE(1, 0,
            { if (t + 2 < NT) STAGE(A,  m0, lda, (long)(t + 2) * 64, &sA[cur][0]); },
            { })
        G256_PHASE(1, 1,
            { if (t + 2 < NT) STAGE(Bt, n0, ldb, (long)(t + 2) * 64, &sB[cur][0]); },
            { if (t < NT - 2) { WVM8(); } else if (t == NT - 2) { WVM4(); } })  // next-tile kh0 resident
    }

    // epilogue: C/D layout col = lane&15, row = (lane>>4)*4 + reg
#pragma unroll
    for (int mi = 0; mi < 8; mi++) {
#pragma unroll
        for (int nj = 0; nj < 4; nj++) {
            f32x4 v = acc[mi][nj];
            const long col   = n0 + wcn * 64 + nj * 16 + (l & 15);
            const long row0r = m0 + wr * 128 + mi * 16 + ((l >> 4) * 4);
#pragma unroll
            for (int e = 0; e < 4; e++) {
                const long row = row0r + e;
                const long idx = row * (long)ldc + col;
                const float val = v[e];
                if constexpr (EPI == EPI_BF16) {
                    ((bf16_t*)Cout)[idx] = (bf16_t)val;
                } else if constexpr (EPI == EPI_RES) {
                    const int b = (int)(row / rowsPerB);
                    ((float*)Cout)[idx] = res[row * (long)ldc + col] + val * gate[(long)b * gateStride + col];
                } else if constexpr (EPI == EPI_GELU) {
                    const float gl = 0.5f * val * (1.f + tanhf(0.7978845608f * (val + 0.044715f * val * val * val)));
                    ((bf16_t*)Cout)[idx] = (bf16_t)gl;
                } else if constexpr (EPI == EPI_MUL) {
                    ((bf16_t*)Cout)[idx] = (bf16_t)((float)aux[idx] * val);
                }
            }
        }
    }
}

// ---------------------------------------------------------------------------
// 128x128 m97-structure GEMM (kept for KV-proj / QK / PV)
// ---------------------------------------------------------------------------
template<int EPI, int CAUSAL>
__global__ __launch_bounds__(256)
void gemm_bt(const bf16_t* __restrict__ A, const bf16_t* __restrict__ Bt,
             void* __restrict__ Cout,
             int M, int N, int Kd, int lda, int ldb, int ldc,
             long sAz, long sBz, long sCz,
             const float* __restrict__ res, const float* __restrict__ gate,
             int gateStride, int rowsPerB, const bf16_t* __restrict__ aux)
{
    const int tid = threadIdx.x;
    const int l   = tid & 63;
    const int w   = tid >> 6;
    const int wr  = w >> 1, wc = w & 1;
    const long m0 = (long)blockIdx.y * 128;
    const long n0 = (long)blockIdx.x * 128;
    const int  z  = blockIdx.z;

    if constexpr (CAUSAL == 1) {
        if (n0 > m0 + 127) return;
    }
    int kend = Kd;
    if constexpr (CAUSAL == 2) {
        const int kc = (int)m0 + 128;
        kend = kc < Kd ? kc : Kd;
    }

    A  += (long)z * sAz;
    Bt += (long)z * sBz;

    __shared__ bf16_t As[128 * 32];
    __shared__ bf16_t Bs[128 * 32];

    const int srow = w * 16 + (l >> 2);
    const int scol = (l & 3) * 8;
    const bf16_t* Ag = A  + (m0 + srow) * (long)lda + scol;
    const bf16_t* Bg = Bt + (n0 + srow) * (long)ldb + scol;

    bf16_t* ldsA = As + w * 512;
    bf16_t* ldsB = Bs + w * 512;

    f32x4 acc[16];
    const f32x4 fz = {0.f, 0.f, 0.f, 0.f};
#pragma unroll
    for (int i = 0; i < 16; i++) acc[i] = fz;

    for (int k0 = 0; k0 < kend; k0 += 32) {
        gload16(Ag + k0,                  ldsA);
        gload16(Ag + k0 + 64 * (long)lda, ldsA + 2048);
        gload16(Bg + k0,                  ldsB);
        gload16(Bg + k0 + 64 * (long)ldb, ldsB + 2048);
        __syncthreads();

        bf16x8 af[4], bfr[4];
#pragma unroll
        for (int f = 0; f < 4; f++) {
            af[f]  = *(const bf16x8*)(As + (wr * 64 + f * 16 + (l & 15)) * 32 + (l >> 4) * 8);
            bfr[f] = *(const bf16x8*)(Bs + (wc * 64 + f * 16 + (l & 15)) * 32 + (l >> 4) * 8);
        }
#pragma unroll
        for (int i = 0; i < 4; i++)
#pragma unroll
            for (int j = 0; j < 4; j++)
                acc[i * 4 + j] = __builtin_amdgcn_mfma_f32_16x16x32_bf16(af[i], bfr[j], acc[i * 4 + j], 0, 0, 0);
        __syncthreads();
    }

#pragma unroll
    for (int i = 0; i < 4; i++) {
#pragma unroll
        for (int j = 0; j < 4; j++) {
            f32x4 v = acc[i * 4 + j];
            const long col  = n0 + wc * 64 + j * 16 + (l & 15);
            const long row0 = m0 + wr * 64 + i * 16 + ((l >> 4) * 4);
#pragma unroll
            for (int e = 0; e < 4; e++) {
                const long row = row0 + e;
                const long idx = row * (long)ldc + col + (long)z * sCz;
                const float val = v[e];
                if constexpr (EPI == EPI_F32) {
                    ((float*)Cout)[idx] = val;
                } else if constexpr (EPI == EPI_BF16) {
                    ((bf16_t*)Cout)[idx] = (bf16_t)val;
                } else if constexpr (EPI == EPI_RES) {
                    const int b = (int)(row / rowsPerB);
                    ((float*)Cout)[idx] = res[row * (long)ldc + col] + val * gate[(long)b * gateStride + col];
                } else if constexpr (EPI == EPI_GELU) {
                    const float gl = 0.5f * val * (1.f + tanhf(0.7978845608f * (val + 0.044715f * val * val * val)));
                    ((bf16_t*)Cout)[idx] = (bf16_t)gl;
                } else {
                    ((bf16_t*)Cout)[idx] = (bf16_t)((float)aux[idx] * val);
                }
            }
        }
    }
}

// fp32 [R,C] -> bf16 [C,R] transpose (batched via blockIdx.z)
__global__ __launch_bounds__(256)
void transpose_f2b(const float* __restrict__ in, bf16_t* __restrict__ out,
                   int R, int C, long inStride, long outStride)
{
    __shared__ float tile[32][33];
    in  += (long)blockIdx.z * inStride;
    out += (long)blockIdx.z * outStride;
    const int c0 = blockIdx.x * 32, r0 = blockIdx.y * 32;
    const int tx = threadIdx.x, ty = threadIdx.y;
#pragma unroll
    for (int i = 0; i < 4; i++)
        tile[ty + i * 8][tx] = in[(long)(r0 + ty + i * 8) * C + c0 + tx];
    __syncthreads();
#pragma unroll
    for (int i = 0; i < 4; i++)
        out[(long)(c0 + ty + i * 8) * R + r0 + tx] = (bf16_t)tile[tx][ty + i * 8];
}

// mod = cond @ Wmod + bmod, two-stage K-split (deterministic)
__global__ __launch_bounds__(256)
void modk_part(const float* __restrict__ cond, const float* __restrict__ W,
               float* __restrict__ part, int D3, int KS)
{
    const int j = blockIdx.x * 256 + threadIdx.x;
    const int b = blockIdx.y;
    const int z = blockIdx.z;
    const float* cb = cond + (long)b * (KS * gridDim.z);
    float s = 0.f;
    const int d0 = z * KS;
#pragma unroll 4
    for (int d = d0; d < d0 + KS; d++) s += cb[d] * W[(long)d * D3 + j];
    part[((long)z * gridDim.y + b) * D3 + j] = s;
}

__global__ __launch_bounds__(256)
void modk_reduce(const float* __restrict__ part, const float* __restrict__ bvec,
                 float* __restrict__ mod, int D3, int NZ)
{
    const int j = blockIdx.x * 256 + threadIdx.x;
    const int b = blockIdx.y;
    float s = bvec[j];
    for (int z = 0; z < NZ; z++) s += part[((long)z * gridDim.y + b) * D3 + j];
    mod[(long)b * D3 + j] = s;
}

// RMSNorm (fp32) + AdaLN scale/shift -> bf16.  One block per row, D=2048.
__global__ __launch_bounds__(256)
void rmsnorm_adaln(const float* __restrict__ xin, const float* __restrict__ mod,
                   bf16_t* __restrict__ out, int D, int T, int D3)
{
    const long row = blockIdx.x;
    const int  b   = (int)(row / T);
    const int  tid = threadIdx.x;
    const float4* x4 = (const float4*)(xin + row * (long)D);
    const float4 v0 = x4[tid], v1 = x4[tid + 256];
    float ss = v0.x * v0.x + v0.y * v0.y + v0.z * v0.z + v0.w * v0.w
             + v1.x * v1.x + v1.y * v1.y + v1.z * v1.z + v1.w * v1.w;
    for (int o = 32; o; o >>= 1) ss += __shfl_down(ss, o, 64);
    __shared__ float red[4];
    if ((tid & 63) == 0) red[tid >> 6] = ss;
    __syncthreads();
    ss = red[0] + red[1] + red[2] + red[3];
    const float rs = rsqrtf(ss / (float)D + 1e-6f);
    const float* sc = mod + (long)b * D3;
    const float* sh = sc + D;
    const float4 s0 = ((const float4*)sc)[tid], s1 = ((const float4*)sc)[tid + 256];
    const float4 h0 = ((const float4*)sh)[tid], h1 = ((const float4*)sh)[tid + 256];
    bf16_t* orow = out + row * (long)D;
    orow[tid * 4 + 0]         = (bf16_t)(v0.x * rs * (1.f + s0.x) + h0.x);
    orow[tid * 4 + 1]         = (bf16_t)(v0.y * rs * (1.f + s0.y) + h0.y);
    orow[tid * 4 + 2]         = (bf16_t)(v0.z * rs * (1.f + s0.z) + h0.z);
    orow[tid * 4 + 3]         = (bf16_t)(v0.w * rs * (1.f + s0.w) + h0.w);
    orow[(tid + 256) * 4 + 0] = (bf16_t)(v1.x * rs * (1.f + s1.x) + h1.x);
    orow[(tid + 256) * 4 + 1] = (bf16_t)(v1.y * rs * (1.f + s1.y) + h1.y);
    orow[(tid + 256) * 4 + 2] = (bf16_t)(v1.z * rs * (1.f + s1.z) + h1.z);
    orow[(tid + 256) * 4 + 3] = (bf16_t)(v1.w * rs * (1.f + s1.w) + h1.w);
}

// RoPE on q (+ H^-0.5 scale), [BT,NH] bf16 -> [B,N,T,H] bf16
__global__ __launch_bounds__(128)
void rope_q(const bf16_t* __restrict__ qp, const float* __restrict__ positions,
            bf16_t* __restrict__ qo, int T, int NH, int H)
{
    const int t = blockIdx.x, n = blockIdx.y, b = blockIdx.z;
    const int i = threadIdx.x;
    const long in0 = ((long)(b * T + t)) * NH + n * H;
    const float x1 = (float)qp[in0 + i];
    const float x2 = (float)qp[in0 + i + 128];
    const float pos = positions[b * T + t];
    const float inv = expf(-9.210340371976184f * (float)i / 128.f);
    float s, c;
    sincosf(pos * inv, &s, &c);
    const float scl = 0.0625f;
    const long out0 = (((long)(b * 8 + n)) * T + t) * H;
    qo[out0 + i]       = (bf16_t)((x1 * c - x2 * s) * scl);
    qo[out0 + i + 128] = (bf16_t)((x2 * c + x1 * s) * scl);
}

// RoPE on k + transpose v.  kvp: [BT,512] bf16 (cols 0..255 k, 256..511 v)
__global__ __launch_bounds__(128)
void rope_kv(const bf16_t* __restrict__ kvp, const float* __restrict__ positions,
             bf16_t* __restrict__ ko, bf16_t* __restrict__ vt, int T, int H, int S)
{
    const int t = blockIdx.x, b = blockIdx.y;
    const int i = threadIdx.x;
    const long in0 = ((long)(b * T + t)) * 512;
    const float k1 = (float)kvp[in0 + i];
    const float k2 = (float)kvp[in0 + i + 128];
    const float pos = positions[b * T + t];
    const float inv = expf(-9.210340371976184f * (float)i / 128.f);
    float s, c;
    sincosf(pos * inv, &s, &c);
    const long ko0 = ((long)(b * T + t)) * H;
    ko[ko0 + i]       = (bf16_t)(k1 * c - k2 * s);
    ko[ko0 + i + 128] = (bf16_t)(k2 * c + k1 * s);
    vt[((long)b * H + i) * S + t]       = kvp[in0 + 256 + i];
    vt[((long)b * H + i + 128) * S + t] = kvp[in0 + 256 + i + 128];
}

// causal mask + softmax over rows of scores [G,T,S] fp32 -> probs bf16.
__global__ __launch_bounds__(256)
void softmax_causal(const float* __restrict__ sc, bf16_t* __restrict__ pr, int T, int S)
{
    const int t = blockIdx.x, g = blockIdx.y;
    const long row = (long)g * T + t;
    const float* srow = sc + row * S;
    bf16_t* prow = pr + row * S;
    const int tid = threadIdx.x;
    const int limit = t | 127;
    const int nch = (limit >> 8) + 1;
    float vals[8];
    float mx = -3.4e38f;
    for (int i = 0; i < nch; i++) {
        const int s = i * 256 + tid;
        const float v = (s <= t) ? srow[s] : -3.4e38f;
        vals[i] = v;
        mx = fmaxf(mx, v);
    }
    for (int o = 32; o; o >>= 1) mx = fmaxf(mx, __shfl_down(mx, o, 64));
    __shared__ float red[4];
    if ((tid & 63) == 0) red[tid >> 6] = mx;
    __syncthreads();
    mx = fmaxf(fmaxf(red[0], red[1]), fmaxf(red[2], red[3]));
    __syncthreads();
    float sum = 0.f;
    for (int i = 0; i < nch; i++) {
        const int s = i * 256 + tid;
        const float e = (s <= t) ? __expf(vals[i] - mx) : 0.f;
        vals[i] = e;
        sum += e;
    }
    for (int o = 32; o; o >>= 1) sum += __shfl_down(sum, o, 64);
    if ((tid & 63) == 0) red[tid >> 6] = sum;
    __syncthreads();
    sum = red[0] + red[1] + red[2] + red[3];
    const float invs = 1.f / sum;
    for (int i = 0; i < nch; i++)
        prow[i * 256 + tid] = (bf16_t)(vals[i] * invs);
}

extern "C" void kernel_launch(void* const* d_in, const int* in_sizes, int n_in,
                              void* d_out, int out_size, void* d_ws, size_t ws_size,
                              hipStream_t stream)
{
    const float* x      = (const float*)d_in[0];
    const float* pos    = (const float*)d_in[1];
    const float* cond   = (const float*)d_in[3];
    const float* Wmod_a = (const float*)d_in[4];
    const float* bmod_a = (const float*)d_in[5];
    const float* Wq     = (const float*)d_in[6];
    const float* Wkv    = (const float*)d_in[7];
    const float* Wo     = (const float*)d_in[8];
    const float* Wmod_f = (const float*)d_in[9];
    const float* bmod_f = (const float*)d_in[10];
    const float* Wg     = (const float*)d_in[11];
    const float* Wl     = (const float*)d_in[12];

    constexpr int  Bb = 2, T = 2048, D = 2048, F = 16384, Nh = 8, H = 256;
    constexpr int  NH = 2048, S = 2048, G = 8, BT = 4096, D3 = 6144;
    constexpr int  KSLICE = 64, NZ = D / KSLICE;

    char* ws = (char*)d_ws;
    size_t off = 0;
    auto alloc = [&](size_t bytes) { char* p = ws + off; off += bytes; return p; };

    bf16_t* WQT  = (bf16_t*)alloc((size_t)NH * D * 2);
    bf16_t* WKVT = (bf16_t*)alloc((size_t)512 * D * 2);
    bf16_t* WOT  = (bf16_t*)alloc((size_t)D * NH * 2);
    bf16_t* WGT  = (bf16_t*)alloc((size_t)2 * F * D * 2);
    bf16_t* WLT  = (bf16_t*)alloc((size_t)D * F * 2);
    float*  MODA = (float*)alloc((size_t)Bb * D3 * 4);
    float*  MODF = (float*)alloc((size_t)Bb * D3 * 4);
    float*  PART = (float*)alloc((size_t)NZ * Bb * D3 * 4);
    bf16_t* NA   = (bf16_t*)alloc((size_t)BT * D * 2);
    bf16_t* QP   = (bf16_t*)alloc((size_t)BT * NH * 2);
    bf16_t* KVP  = (bf16_t*)alloc((size_t)BT * 512 * 2);
    bf16_t* Qr   = (bf16_t*)alloc((size_t)Bb * Nh * T * H * 2);
    bf16_t* Kr   = (bf16_t*)alloc((size_t)Bb * T * H * 2);
    bf16_t* VT   = (bf16_t*)alloc((size_t)Bb * H * S * 2);
    bf16_t* ENC  = (bf16_t*)alloc((size_t)BT * NH * 2);
    float*  X1   = (float*)alloc((size_t)BT * D * 4);
    bf16_t* NF   = (bf16_t*)alloc((size_t)BT * D * 2);
    const size_t scBytes = (size_t)G * T * S * 4;
    const size_t prBytes = (size_t)G * T * S * 2;
    const size_t hBytes  = (size_t)BT * F * 2;
    const size_t bigBytes = (scBytes + prBytes > hBytes) ? (scBytes + prBytes) : hBytes;
    char* big = alloc(bigBytes);
    float*  SC = (float*)big;
    bf16_t* PR = (bf16_t*)(big + scBytes);
    bf16_t* Hb = (bf16_t*)big;
    (void)ws_size; (void)in_sizes; (void)n_in; (void)out_size;

    const dim3 tb(32, 8);
    transpose_f2b<<<dim3(H / 32, D / 32, 8), tb, 0, stream>>>(Wq,  WQT,  D,  H, (long)D * H, (long)H * D);
    transpose_f2b<<<dim3(H / 32, D / 32, 2), tb, 0, stream>>>(Wkv, WKVT, D,  H, (long)D * H, (long)H * D);
    transpose_f2b<<<dim3(D / 32, NH / 32, 1), tb, 0, stream>>>(Wo, WOT, NH,  D, 0, 0);
    transpose_f2b<<<dim3(F / 32, D / 32, 2), tb, 0, stream>>>(Wg,  WGT,  D,  F, (long)D * F, (long)F * D);
    transpose_f2b<<<dim3(D / 32, F / 32, 1), tb, 0, stream>>>(Wl,  WLT,  F,  D, 0, 0);
    modk_part<<<dim3(D3 / 256, Bb, NZ), 256, 0, stream>>>(cond, Wmod_a, PART, D3, KSLICE);
    modk_reduce<<<dim3(D3 / 256, Bb), 256, 0, stream>>>(PART, bmod_a, MODA, D3, NZ);
    modk_part<<<dim3(D3 / 256, Bb, NZ), 256, 0, stream>>>(cond, Wmod_f, PART, D3, KSLICE);
    modk_reduce<<<dim3(D3 / 256, Bb), 256, 0, stream>>>(PART, bmod_f, MODF, D3, NZ);
    rmsnorm_adaln<<<BT, 256, 0, stream>>>(x, MODA, NA, D, T, D3);
    // Q projection (256^2 8-phase)
    gemm256<EPI_BF16><<<dim3(NH / 256, BT / 256), 512, 0, stream>>>(
        NA, WQT, QP, D, D, D, NH, nullptr, nullptr, 0, 0, nullptr);
    // KV projection (N=512 -> keep 128^2)
    gemm_bt<EPI_BF16, 0><<<dim3(512 / 128, BT / 128, 1), 256, 0, stream>>>(
        NA, WKVT, KVP, BT, 512, D, D, D, 512, 0, 0, 0, nullptr, nullptr, 0, 0, nullptr);
    rope_q<<<dim3(T, Nh, Bb), 128, 0, stream>>>(QP, pos, Qr, T, NH, H);
    rope_kv<<<dim3(T, Bb), 128, 0, stream>>>(KVP, pos, Kr, VT, T, H, S);
    for (int b = 0; b < Bb; b++) {
        gemm_bt<EPI_F32, 1><<<dim3(S / 128, T / 128, G), 256, 0, stream>>>(
            Qr + (long)b * Nh * T * H, Kr + (long)b * T * H, SC,
            T, S, H, H, H, S, (long)T * H, 0, (long)T * S, nullptr, nullptr, 0, 0, nullptr);
        softmax_causal<<<dim3(T, G), 256, 0, stream>>>(SC, PR, T, S);
        gemm_bt<EPI_BF16, 2><<<dim3(H / 128, T / 128, G), 256, 0, stream>>>(
            PR, VT + (long)b * H * S, ENC + (long)b * T * NH,
            T, H, S, S, S, NH, (long)T * S, 0, (long)H, nullptr, nullptr, 0, 0, nullptr);
    }
    // Wo projection + gated residual -> x1 (256^2)
    gemm256<EPI_RES><<<dim3(D / 256, BT / 256), 512, 0, stream>>>(
        ENC, WOT, X1, NH, NH, NH, D, x, MODA + 2 * D, D3, T, nullptr);
    rmsnorm_adaln<<<BT, 256, 0, stream>>>(X1, MODF, NF, D, T, D3);
    // FFN up: h0 = gelu(n@Wg0); h = h0 * (n@Wg1) in-place (256^2)
    gemm256<EPI_GELU><<<dim3(F / 256, BT / 256), 512, 0, stream>>>(
        NF, WGT, Hb, D, D, D, F, nullptr, nullptr, 0, 0, nullptr);
    gemm256<EPI_MUL><<<dim3(F / 256, BT / 256), 512, 0, stream>>>(
        NF, WGT + (long)F * D, Hb, D, D, D, F, nullptr, nullptr, 0, 0, Hb);
    // FFN down + gated residual -> out (256^2)
    gemm256<EPI_RES><<<dim3(D / 256, BT / 256), 512, 0, stream>>>(
        Hb, WLT, (float*)d_out, F, F, F, D, X1, MODF + 2 * D, D3, T, nullptr);
}

// Round 5
// 1689.472 us; speedup vs baseline: 2.4107x; 1.1826x over previous
//
#include <hip/hip_runtime.h>
#include <hip/hip_bf16.h>

typedef __bf16 bf16_t;
typedef __bf16 bf16x8 __attribute__((ext_vector_type(8)));
typedef float  f32x4  __attribute__((ext_vector_type(4)));

#define DEV static __device__ __forceinline__

DEV void gload16(const bf16_t* g, bf16_t* l) {
    __builtin_amdgcn_global_load_lds(
        (const __attribute__((address_space(1))) void*)g,
        (__attribute__((address_space(3))) void*)l, 16, 0, 0);
}

enum { EPI_F32 = 0, EPI_BF16 = 1, EPI_RES = 2, EPI_GELU = 3, EPI_MUL = 4 };

// ---------------------------------------------------------------------------
// 256x256-tile, BK=64, 8-wave (2Mx4N), 2-phase GEMM (T3-minimum structure):
// per K-tile: STAGE(t+1) ; 24 ds_read_b128 + 64 MFMA (compiler-scheduled) ;
// one __syncthreads(). LDS [2][256][64] bf16 per matrix, 16B-chunk XOR
// swizzle (chunk ^= row&7) applied on BOTH sides: pre-swizzled global source
// feeding linear global_load_lds, and swizzled ds_read addresses (rule 21).
// Optional split-K via blockIdx.z (kbase = z*Kd, out offset z*sCz).
// ---------------------------------------------------------------------------
template<int EPI>
__global__ __launch_bounds__(512, 1)
void gemm256(const bf16_t* __restrict__ A, const bf16_t* __restrict__ Bt,
             void* __restrict__ Cout, int Kd, int lda, int ldb, int ldc,
             long sCz,
             const float* __restrict__ res, const float* __restrict__ gate,
             int gateStride, int rowsPerB, const bf16_t* __restrict__ aux)
{
    const int nbx = gridDim.x;
    const int nwg = nbx * gridDim.y;
    int lin = blockIdx.y * nbx + blockIdx.x;
    // bijective XCD-chunked swizzle (m204), per z-plane
    const int q8 = nwg >> 3, r8 = nwg & 7;
    const int xcd = lin & 7, oo = lin >> 3;
    lin = (xcd < r8 ? xcd * (q8 + 1) : r8 * (q8 + 1) + (xcd - r8) * q8) + oo;
    const long m0 = (long)(lin / nbx) * 256;
    const long n0 = (long)(lin % nbx) * 256;
    const long kbase = (long)blockIdx.z * Kd;

    const int tid = threadIdx.x;
    const int l   = tid & 63;
    const int w   = tid >> 6;     // 0..7
    const int wr  = w >> 2;       // 0..1 (M half)
    const int wcn = w & 3;        // 0..3 (N quarter)

    __shared__ bf16_t sA[2][256 * 64];
    __shared__ bf16_t sB[2][256 * 64];

    // staging: wave w lane l covers LDS row (w*8 + l>>3) (+64 per L), 16B chunk (l&7).
    // LDS chunk c at row r holds global chunk c ^ (r&7)  -> source chunk = (l&7)^(l>>3).
    const int  srow = w * 8 + (l >> 3);
    const long sgc  = (long)(((l & 7) ^ (l >> 3)) << 3);

    const int NT = Kd >> 6;

    auto STAGE = [&](const bf16_t* __restrict__ G, long row0, int ld, long kt, bf16_t* lb) {
#pragma unroll
        for (int L = 0; L < 4; L++) {
            const long g = (row0 + L * 64 + srow) * (long)ld + kt + sgc;
            gload16(G + g, lb + L * 4096 + w * 512);
        }
    };

    f32x4 acc[8][4];
#pragma unroll
    for (int i = 0; i < 8; i++)
#pragma unroll
        for (int j = 0; j < 4; j++) acc[i][j] = f32x4{0.f, 0.f, 0.f, 0.f};

    STAGE(A,  m0, lda, kbase, &sA[0][0]);
    STAGE(Bt, n0, ldb, kbase, &sB[0][0]);
    __syncthreads();

    const int co0 = ((l >> 4) ^ (l & 7)) << 3;        // kc=0 read chunk (swizzled)
    const int co1 = ((4 + (l >> 4)) ^ (l & 7)) << 3;  // kc=1 read chunk (swizzled)

    for (int t = 0; t < NT; ++t) {
        const int cur = t & 1;
        if (t + 1 < NT) {
            STAGE(A,  m0, lda, kbase + (long)(t + 1) * 64, &sA[cur ^ 1][0]);
            STAGE(Bt, n0, ldb, kbase + (long)(t + 1) * 64, &sB[cur ^ 1][0]);
        }
        const bf16_t* sAc = sA[cur];
        const bf16_t* sBc = sB[cur];
        bf16x8 a0[8], a1[8], b0[4], b1[4];
#pragma unroll
        for (int mi = 0; mi < 8; mi++) {
            const int row = wr * 128 + mi * 16 + (l & 15);
            a0[mi] = *(const bf16x8*)(&sAc[row * 64 + co0]);
            a1[mi] = *(const bf16x8*)(&sAc[row * 64 + co1]);
        }
#pragma unroll
        for (int nj = 0; nj < 4; nj++) {
            const int row = wcn * 64 + nj * 16 + (l & 15);
            b0[nj] = *(const bf16x8*)(&sBc[row * 64 + co0]);
            b1[nj] = *(const bf16x8*)(&sBc[row * 64 + co1]);
        }
#pragma unroll
        for (int mi = 0; mi < 8; mi++)
#pragma unroll
            for (int nj = 0; nj < 4; nj++)
                acc[mi][nj] = __builtin_amdgcn_mfma_f32_16x16x32_bf16(a0[mi], b0[nj], acc[mi][nj], 0, 0, 0);
#pragma unroll
        for (int mi = 0; mi < 8; mi++)
#pragma unroll
            for (int nj = 0; nj < 4; nj++)
                acc[mi][nj] = __builtin_amdgcn_mfma_f32_16x16x32_bf16(a1[mi], b1[nj], acc[mi][nj], 0, 0, 0);
        __syncthreads();
    }

    // epilogue: C/D layout col = lane&15, row = (lane>>4)*4 + reg
#pragma unroll
    for (int mi = 0; mi < 8; mi++) {
#pragma unroll
        for (int nj = 0; nj < 4; nj++) {
            f32x4 v = acc[mi][nj];
            const long col   = n0 + wcn * 64 + nj * 16 + (l & 15);
            const long row0r = m0 + wr * 128 + mi * 16 + ((l >> 4) * 4);
#pragma unroll
            for (int e = 0; e < 4; e++) {
                const long row = row0r + e;
                const long idx = row * (long)ldc + col + (long)blockIdx.z * sCz;
                const float val = v[e];
                if constexpr (EPI == EPI_F32) {
                    ((float*)Cout)[idx] = val;
                } else if constexpr (EPI == EPI_BF16) {
                    ((bf16_t*)Cout)[idx] = (bf16_t)val;
                } else if constexpr (EPI == EPI_RES) {
                    const int b = (int)(row / rowsPerB);
                    ((float*)Cout)[idx] = res[row * (long)ldc + col] + val * gate[(long)b * gateStride + col];
                } else if constexpr (EPI == EPI_GELU) {
                    const float gl = 0.5f * val * (1.f + tanhf(0.7978845608f * (val + 0.044715f * val * val * val)));
                    ((bf16_t*)Cout)[idx] = (bf16_t)gl;
                } else if constexpr (EPI == EPI_MUL) {
                    ((bf16_t*)Cout)[idx] = (bf16_t)((float)aux[idx] * val);
                }
            }
        }
    }
}

// out = X1 + (P[z=0] + P[z=1]) * gate   (split-K combine, fp32, float4)
__global__ __launch_bounds__(256)
void combine_splitk(const float* __restrict__ P, const float* __restrict__ X1,
                    const float* __restrict__ gate, float* __restrict__ out,
                    int D, int T, int gateStride, long zstride, long n4)
{
    for (long i4 = (long)blockIdx.x * 256 + threadIdx.x; i4 < n4; i4 += (long)gridDim.x * 256) {
        const long i = i4 * 4;
        const float4 p0 = *(const float4*)(P + i);
        const float4 p1 = *(const float4*)(P + i + zstride);
        const float4 xv = *(const float4*)(X1 + i);
        const long row = i / D;
        const int  b   = (int)(row / T);
        const int  col = (int)(i - row * D);
        const float* gp = gate + (long)b * gateStride + col;
        float4 r;
        r.x = xv.x + (p0.x + p1.x) * gp[0];
        r.y = xv.y + (p0.y + p1.y) * gp[1];
        r.z = xv.z + (p0.z + p1.z) * gp[2];
        r.w = xv.w + (p0.w + p1.w) * gp[3];
        *(float4*)(out + i) = r;
    }
}

// ---------------------------------------------------------------------------
// 128x128 m97-structure GEMM (KV-proj / QK / PV)
// ---------------------------------------------------------------------------
template<int EPI, int CAUSAL>
__global__ __launch_bounds__(256)
void gemm_bt(const bf16_t* __restrict__ A, const bf16_t* __restrict__ Bt,
             void* __restrict__ Cout,
             int M, int N, int Kd, int lda, int ldb, int ldc,
             long sAz, long sBz, long sCz,
             const float* __restrict__ res, const float* __restrict__ gate,
             int gateStride, int rowsPerB, const bf16_t* __restrict__ aux)
{
    const int tid = threadIdx.x;
    const int l   = tid & 63;
    const int w   = tid >> 6;
    const int wr  = w >> 1, wc = w & 1;
    const long m0 = (long)blockIdx.y * 128;
    const long n0 = (long)blockIdx.x * 128;
    const int  z  = blockIdx.z;

    if constexpr (CAUSAL == 1) {
        if (n0 > m0 + 127) return;
    }
    int kend = Kd;
    if constexpr (CAUSAL == 2) {
        const int kc = (int)m0 + 128;
        kend = kc < Kd ? kc : Kd;
    }

    A  += (long)z * sAz;
    Bt += (long)z * sBz;

    __shared__ bf16_t As[128 * 32];
    __shared__ bf16_t Bs[128 * 32];

    const int srow = w * 16 + (l >> 2);
    const int scol = (l & 3) * 8;
    const bf16_t* Ag = A  + (m0 + srow) * (long)lda + scol;
    const bf16_t* Bg = Bt + (n0 + srow) * (long)ldb + scol;

    bf16_t* ldsA = As + w * 512;
    bf16_t* ldsB = Bs + w * 512;

    f32x4 acc[16];
    const f32x4 fz = {0.f, 0.f, 0.f, 0.f};
#pragma unroll
    for (int i = 0; i < 16; i++) acc[i] = fz;

    for (int k0 = 0; k0 < kend; k0 += 32) {
        gload16(Ag + k0,                  ldsA);
        gload16(Ag + k0 + 64 * (long)lda, ldsA + 2048);
        gload16(Bg + k0,                  ldsB);
        gload16(Bg + k0 + 64 * (long)ldb, ldsB + 2048);
        __syncthreads();

        bf16x8 af[4], bfr[4];
#pragma unroll
        for (int f = 0; f < 4; f++) {
            af[f]  = *(const bf16x8*)(As + (wr * 64 + f * 16 + (l & 15)) * 32 + (l >> 4) * 8);
            bfr[f] = *(const bf16x8*)(Bs + (wc * 64 + f * 16 + (l & 15)) * 32 + (l >> 4) * 8);
        }
#pragma unroll
        for (int i = 0; i < 4; i++)
#pragma unroll
            for (int j = 0; j < 4; j++)
                acc[i * 4 + j] = __builtin_amdgcn_mfma_f32_16x16x32_bf16(af[i], bfr[j], acc[i * 4 + j], 0, 0, 0);
        __syncthreads();
    }

#pragma unroll
    for (int i = 0; i < 4; i++) {
#pragma unroll
        for (int j = 0; j < 4; j++) {
            f32x4 v = acc[i * 4 + j];
            const long col  = n0 + wc * 64 + j * 16 + (l & 15);
            const long row0 = m0 + wr * 64 + i * 16 + ((l >> 4) * 4);
#pragma unroll
            for (int e = 0; e < 4; e++) {
                const long row = row0 + e;
                const long idx = row * (long)ldc + col + (long)z * sCz;
                const float val = v[e];
                if constexpr (EPI == EPI_F32) {
                    ((float*)Cout)[idx] = val;
                } else if constexpr (EPI == EPI_BF16) {
                    ((bf16_t*)Cout)[idx] = (bf16_t)val;
                } else if constexpr (EPI == EPI_RES) {
                    const int b = (int)(row / rowsPerB);
                    ((float*)Cout)[idx] = res[row * (long)ldc + col] + val * gate[(long)b * gateStride + col];
                } else if constexpr (EPI == EPI_GELU) {
                    const float gl = 0.5f * val * (1.f + tanhf(0.7978845608f * (val + 0.044715f * val * val * val)));
                    ((bf16_t*)Cout)[idx] = (bf16_t)gl;
                } else {
                    ((bf16_t*)Cout)[idx] = (bf16_t)((float)aux[idx] * val);
                }
            }
        }
    }
}

// fp32 [R,C] -> bf16 [C,R] transpose (batched via blockIdx.z)
__global__ __launch_bounds__(256)
void transpose_f2b(const float* __restrict__ in, bf16_t* __restrict__ out,
                   int R, int C, long inStride, long outStride)
{
    __shared__ float tile[32][33];
    in  += (long)blockIdx.z * inStride;
    out += (long)blockIdx.z * outStride;
    const int c0 = blockIdx.x * 32, r0 = blockIdx.y * 32;
    const int tx = threadIdx.x, ty = threadIdx.y;
#pragma unroll
    for (int i = 0; i < 4; i++)
        tile[ty + i * 8][tx] = in[(long)(r0 + ty + i * 8) * C + c0 + tx];
    __syncthreads();
#pragma unroll
    for (int i = 0; i < 4; i++)
        out[(long)(c0 + ty + i * 8) * R + r0 + tx] = (bf16_t)tile[tx][ty + i * 8];
}

// mod = cond @ Wmod + bmod, two-stage K-split (deterministic)
__global__ __launch_bounds__(256)
void modk_part(const float* __restrict__ cond, const float* __restrict__ W,
               float* __restrict__ part, int D3, int KS)
{
    const int j = blockIdx.x * 256 + threadIdx.x;
    const int b = blockIdx.y;
    const int z = blockIdx.z;
    const float* cb = cond + (long)b * (KS * gridDim.z);
    float s = 0.f;
    const int d0 = z * KS;
#pragma unroll 4
    for (int d = d0; d < d0 + KS; d++) s += cb[d] * W[(long)d * D3 + j];
    part[((long)z * gridDim.y + b) * D3 + j] = s;
}

__global__ __launch_bounds__(256)
void modk_reduce(const float* __restrict__ part, const float* __restrict__ bvec,
                 float* __restrict__ mod, int D3, int NZ)
{
    const int j = blockIdx.x * 256 + threadIdx.x;
    const int b = blockIdx.y;
    float s = bvec[j];
    for (int z = 0; z < NZ; z++) s += part[((long)z * gridDim.y + b) * D3 + j];
    mod[(long)b * D3 + j] = s;
}

// RMSNorm (fp32) + AdaLN scale/shift -> bf16.  One block per row, D=2048.
__global__ __launch_bounds__(256)
void rmsnorm_adaln(const float* __restrict__ xin, const float* __restrict__ mod,
                   bf16_t* __restrict__ out, int D, int T, int D3)
{
    const long row = blockIdx.x;
    const int  b   = (int)(row / T);
    const int  tid = threadIdx.x;
    const float4* x4 = (const float4*)(xin + row * (long)D);
    const float4 v0 = x4[tid], v1 = x4[tid + 256];
    float ss = v0.x * v0.x + v0.y * v0.y + v0.z * v0.z + v0.w * v0.w
             + v1.x * v1.x + v1.y * v1.y + v1.z * v1.z + v1.w * v1.w;
    for (int o = 32; o; o >>= 1) ss += __shfl_down(ss, o, 64);
    __shared__ float red[4];
    if ((tid & 63) == 0) red[tid >> 6] = ss;
    __syncthreads();
    ss = red[0] + red[1] + red[2] + red[3];
    const float rs = rsqrtf(ss / (float)D + 1e-6f);
    const float* sc = mod + (long)b * D3;
    const float* sh = sc + D;
    const float4 s0 = ((const float4*)sc)[tid], s1 = ((const float4*)sc)[tid + 256];
    const float4 h0 = ((const float4*)sh)[tid], h1 = ((const float4*)sh)[tid + 256];
    bf16_t* orow = out + row * (long)D;
    orow[tid * 4 + 0]         = (bf16_t)(v0.x * rs * (1.f + s0.x) + h0.x);
    orow[tid * 4 + 1]         = (bf16_t)(v0.y * rs * (1.f + s0.y) + h0.y);
    orow[tid * 4 + 2]         = (bf16_t)(v0.z * rs * (1.f + s0.z) + h0.z);
    orow[tid * 4 + 3]         = (bf16_t)(v0.w * rs * (1.f + s0.w) + h0.w);
    orow[(tid + 256) * 4 + 0] = (bf16_t)(v1.x * rs * (1.f + s1.x) + h1.x);
    orow[(tid + 256) * 4 + 1] = (bf16_t)(v1.y * rs * (1.f + s1.y) + h1.y);
    orow[(tid + 256) * 4 + 2] = (bf16_t)(v1.z * rs * (1.f + s1.z) + h1.z);
    orow[(tid + 256) * 4 + 3] = (bf16_t)(v1.w * rs * (1.f + s1.w) + h1.w);
}

// RoPE on q (+ H^-0.5 scale), [BT,NH] bf16 -> [B,N,T,H] bf16
__global__ __launch_bounds__(128)
void rope_q(const bf16_t* __restrict__ qp, const float* __restrict__ positions,
            bf16_t* __restrict__ qo, int T, int NH, int H)
{
    const int t = blockIdx.x, n = blockIdx.y, b = blockIdx.z;
    const int i = threadIdx.x;
    const long in0 = ((long)(b * T + t)) * NH + n * H;
    const float x1 = (float)qp[in0 + i];
    const float x2 = (float)qp[in0 + i + 128];
    const float pos = positions[b * T + t];
    const float inv = expf(-9.210340371976184f * (float)i / 128.f);
    float s, c;
    sincosf(pos * inv, &s, &c);
    const float scl = 0.0625f;
    const long out0 = (((long)(b * 8 + n)) * T + t) * H;
    qo[out0 + i]       = (bf16_t)((x1 * c - x2 * s) * scl);
    qo[out0 + i + 128] = (bf16_t)((x2 * c + x1 * s) * scl);
}

// RoPE on k + transpose v.  kvp: [BT,512] bf16 (cols 0..255 k, 256..511 v)
__global__ __launch_bounds__(128)
void rope_kv(const bf16_t* __restrict__ kvp, const float* __restrict__ positions,
             bf16_t* __restrict__ ko, bf16_t* __restrict__ vt, int T, int H, int S)
{
    const int t = blockIdx.x, b = blockIdx.y;
    const int i = threadIdx.x;
    const long in0 = ((long)(b * T + t)) * 512;
    const float k1 = (float)kvp[in0 + i];
    const float k2 = (float)kvp[in0 + i + 128];
    const float pos = positions[b * T + t];
    const float inv = expf(-9.210340371976184f * (float)i / 128.f);
    float s, c;
    sincosf(pos * inv, &s, &c);
    const long ko0 = ((long)(b * T + t)) * H;
    ko[ko0 + i]       = (bf16_t)(k1 * c - k2 * s);
    ko[ko0 + i + 128] = (bf16_t)(k2 * c + k1 * s);
    vt[((long)b * H + i) * S + t]       = kvp[in0 + 256 + i];
    vt[((long)b * H + i + 128) * S + t] = kvp[in0 + 256 + i + 128];
}

// causal mask + softmax over rows of scores [G,T,S] fp32 -> probs bf16.
__global__ __launch_bounds__(256)
void softmax_causal(const float* __restrict__ sc, bf16_t* __restrict__ pr, int T, int S)
{
    const int t = blockIdx.x, g = blockIdx.y;
    const long row = (long)g * T + t;
    const float* srow = sc + row * S;
    bf16_t* prow = pr + row * S;
    const int tid = threadIdx.x;
    const int limit = t | 127;
    const int nch = (limit >> 8) + 1;
    float vals[8];
    float mx = -3.4e38f;
    for (int i = 0; i < nch; i++) {
        const int s = i * 256 + tid;
        const float v = (s <= t) ? srow[s] : -3.4e38f;
        vals[i] = v;
        mx = fmaxf(mx, v);
    }
    for (int o = 32; o; o >>= 1) mx = fmaxf(mx, __shfl_down(mx, o, 64));
    __shared__ float red[4];
    if ((tid & 63) == 0) red[tid >> 6] = mx;
    __syncthreads();
    mx = fmaxf(fmaxf(red[0], red[1]), fmaxf(red[2], red[3]));
    __syncthreads();
    float sum = 0.f;
    for (int i = 0; i < nch; i++) {
        const int s = i * 256 + tid;
        const float e = (s <= t) ? __expf(vals[i] - mx) : 0.f;
        vals[i] = e;
        sum += e;
    }
    for (int o = 32; o; o >>= 1) sum += __shfl_down(sum, o, 64);
    if ((tid & 63) == 0) red[tid >> 6] = sum;
    __syncthreads();
    sum = red[0] + red[1] + red[2] + red[3];
    const float invs = 1.f / sum;
    for (int i = 0; i < nch; i++)
        prow[i * 256 + tid] = (bf16_t)(vals[i] * invs);
}

extern "C" void kernel_launch(void* const* d_in, const int* in_sizes, int n_in,
                              void* d_out, int out_size, void* d_ws, size_t ws_size,
                              hipStream_t stream)
{
    const float* x      = (const float*)d_in[0];
    const float* pos    = (const float*)d_in[1];
    const float* cond   = (const float*)d_in[3];
    const float* Wmod_a = (const float*)d_in[4];
    const float* bmod_a = (const float*)d_in[5];
    const float* Wq     = (const float*)d_in[6];
    const float* Wkv    = (const float*)d_in[7];
    const float* Wo     = (const float*)d_in[8];
    const float* Wmod_f = (const float*)d_in[9];
    const float* bmod_f = (const float*)d_in[10];
    const float* Wg     = (const float*)d_in[11];
    const float* Wl     = (const float*)d_in[12];

    constexpr int  Bb = 2, T = 2048, D = 2048, F = 16384, Nh = 8, H = 256;
    constexpr int  NH = 2048, S = 2048, G = 8, BT = 4096, D3 = 6144;
    constexpr int  KSLICE = 64, NZ = D / KSLICE;

    char* ws = (char*)d_ws;
    size_t off = 0;
    auto alloc = [&](size_t bytes) { char* p = ws + off; off += bytes; return p; };

    bf16_t* WQT  = (bf16_t*)alloc((size_t)NH * D * 2);
    bf16_t* WKVT = (bf16_t*)alloc((size_t)512 * D * 2);
    bf16_t* WOT  = (bf16_t*)alloc((size_t)D * NH * 2);
    bf16_t* WGT  = (bf16_t*)alloc((size_t)2 * F * D * 2);
    bf16_t* WLT  = (bf16_t*)alloc((size_t)D * F * 2);
    float*  MODA = (float*)alloc((size_t)Bb * D3 * 4);
    float*  MODF = (float*)alloc((size_t)Bb * D3 * 4);
    float*  PART = (float*)alloc((size_t)NZ * Bb * D3 * 4);
    bf16_t* NA   = (bf16_t*)alloc((size_t)BT * D * 2);
    bf16_t* QP   = (bf16_t*)alloc((size_t)BT * NH * 2);
    bf16_t* KVP  = (bf16_t*)alloc((size_t)BT * 512 * 2);
    bf16_t* Qr   = (bf16_t*)alloc((size_t)Bb * Nh * T * H * 2);
    bf16_t* Kr   = (bf16_t*)alloc((size_t)Bb * T * H * 2);
    bf16_t* VT   = (bf16_t*)alloc((size_t)Bb * H * S * 2);
    bf16_t* ENC  = (bf16_t*)alloc((size_t)BT * NH * 2);
    float*  X1   = (float*)alloc((size_t)BT * D * 4);
    bf16_t* NF   = (bf16_t*)alloc((size_t)BT * D * 2);
    const size_t scBytes = (size_t)G * T * S * 4;   // 128 MB
    const size_t prBytes = (size_t)G * T * S * 2;   //  64 MB
    const size_t hBytes  = (size_t)BT * F * 2;      // 128 MB
    const size_t bigBytes = (scBytes + prBytes > hBytes) ? (scBytes + prBytes) : hBytes;
    char* big = alloc(bigBytes);
    float*  SC = (float*)big;
    bf16_t* PR = (bf16_t*)(big + scBytes);
    bf16_t* Hb = (bf16_t*)big;                       // aliases SC/PR
    float*  PARTK = (float*)(big + hBytes);          // 64 MB tail: split-K partials
    (void)ws_size; (void)in_sizes; (void)n_in; (void)out_size;

    const dim3 tb(32, 8);
    transpose_f2b<<<dim3(H / 32, D / 32, 8), tb, 0, stream>>>(Wq,  WQT,  D,  H, (long)D * H, (long)H * D);
    transpose_f2b<<<dim3(H / 32, D / 32, 2), tb, 0, stream>>>(Wkv, WKVT, D,  H, (long)D * H, (long)H * D);
    transpose_f2b<<<dim3(D / 32, NH / 32, 1), tb, 0, stream>>>(Wo, WOT, NH,  D, 0, 0);
    transpose_f2b<<<dim3(F / 32, D / 32, 2), tb, 0, stream>>>(Wg,  WGT,  D,  F, (long)D * F, (long)F * D);
    transpose_f2b<<<dim3(D / 32, F / 32, 1), tb, 0, stream>>>(Wl,  WLT,  F,  D, 0, 0);
    modk_part<<<dim3(D3 / 256, Bb, NZ), 256, 0, stream>>>(cond, Wmod_a, PART, D3, KSLICE);
    modk_reduce<<<dim3(D3 / 256, Bb), 256, 0, stream>>>(PART, bmod_a, MODA, D3, NZ);
    modk_part<<<dim3(D3 / 256, Bb, NZ), 256, 0, stream>>>(cond, Wmod_f, PART, D3, KSLICE);
    modk_reduce<<<dim3(D3 / 256, Bb), 256, 0, stream>>>(PART, bmod_f, MODF, D3, NZ);
    rmsnorm_adaln<<<BT, 256, 0, stream>>>(x, MODA, NA, D, T, D3);
    // Q projection (256^2, 2-phase)
    gemm256<EPI_BF16><<<dim3(NH / 256, BT / 256, 1), 512, 0, stream>>>(
        NA, WQT, QP, D, D, D, NH, 0, nullptr, nullptr, 0, 0, nullptr);
    // KV projection (N=512 -> 128^2)
    gemm_bt<EPI_BF16, 0><<<dim3(512 / 128, BT / 128, 1), 256, 0, stream>>>(
        NA, WKVT, KVP, BT, 512, D, D, D, 512, 0, 0, 0, nullptr, nullptr, 0, 0, nullptr);
    rope_q<<<dim3(T, Nh, Bb), 128, 0, stream>>>(QP, pos, Qr, T, NH, H);
    rope_kv<<<dim3(T, Bb), 128, 0, stream>>>(KVP, pos, Kr, VT, T, H, S);
    for (int b = 0; b < Bb; b++) {
        gemm_bt<EPI_F32, 1><<<dim3(S / 128, T / 128, G), 256, 0, stream>>>(
            Qr + (long)b * Nh * T * H, Kr + (long)b * T * H, SC,
            T, S, H, H, H, S, (long)T * H, 0, (long)T * S, nullptr, nullptr, 0, 0, nullptr);
        softmax_causal<<<dim3(T, G), 256, 0, stream>>>(SC, PR, T, S);
        gemm_bt<EPI_BF16, 2><<<dim3(H / 128, T / 128, G), 256, 0, stream>>>(
            PR, VT + (long)b * H * S, ENC + (long)b * T * NH,
            T, H, S, S, S, NH, (long)T * S, 0, (long)H, nullptr, nullptr, 0, 0, nullptr);
    }
    // Wo projection + gated residual -> x1 (256^2)
    gemm256<EPI_RES><<<dim3(D / 256, BT / 256, 1), 512, 0, stream>>>(
        ENC, WOT, X1, NH, NH, NH, D, 0, x, MODA + 2 * D, D3, T, nullptr);
    rmsnorm_adaln<<<BT, 256, 0, stream>>>(X1, MODF, NF, D, T, D3);
    // FFN up: h0 = gelu(n@Wg0); h = h0 * (n@Wg1) in-place (256^2)
    gemm256<EPI_GELU><<<dim3(F / 256, BT / 256, 1), 512, 0, stream>>>(
        NF, WGT, Hb, D, D, D, F, 0, nullptr, nullptr, 0, 0, nullptr);
    gemm256<EPI_MUL><<<dim3(F / 256, BT / 256, 1), 512, 0, stream>>>(
        NF, WGT + (long)F * D, Hb, D, D, D, F, 0, nullptr, nullptr, 0, 0, Hb);
    // FFN down: split-K=2 partials (full-GPU grid), then fused combine -> out
    gemm256<EPI_F32><<<dim3(D / 256, BT / 256, 2), 512, 0, stream>>>(
        Hb, WLT, PARTK, F / 2, F, F, D, (long)BT * D, nullptr, nullptr, 0, 0, nullptr);
    combine_splitk<<<2048, 256, 0, stream>>>(
        PARTK, X1, MODF + 2 * D, (float*)d_out, D, T, D3, (long)BT * D, (long)BT * D / 4);
}